// Round 10
// baseline (211.940 us; speedup 1.0000x reference)
//
#include <hip/hip_runtime.h>
#include <math.h>

#define N 4096
#define D 512
#define TOPK 10
#define TOPK_HALF 5
#define NT 32
#define TRI_BLOCKS (NT * (NT + 1) / 2)   // 528
#define WC_BLOCKS (N * TOPK_HALF / 4)
#define INV_N (1.0f / 4096.0f)

typedef __bf16 bf16;
typedef __bf16 bf16x8 __attribute__((ext_vector_type(8)));
typedef float f32x4 __attribute__((ext_vector_type(4)));
typedef _Float16 f16;
typedef _Float16 f16x4 __attribute__((ext_vector_type(4)));
typedef _Float16 f16x8 __attribute__((ext_vector_type(8)));
typedef unsigned short u16;
typedef unsigned short u16x8 __attribute__((ext_vector_type(8)));
typedef unsigned int u32;

__device__ __forceinline__ void gl_lds16(const void* g, void* l) {
  __builtin_amdgcn_global_load_lds(
      (const __attribute__((address_space(1))) void*)g,
      (__attribute__((address_space(3))) void*)l, 16, 0, 0);
}

__device__ __forceinline__ float f16tof(u16 h) {
  return (float)__builtin_bit_cast(_Float16, h);
}

// ---------------- K0: L2-normalize both matrices ----------------
__global__ __launch_bounds__(256) void k_normalize2(const float* __restrict__ xs,
                                                    const float* __restrict__ xt,
                                                    bf16* __restrict__ ys,
                                                    bf16* __restrict__ yt,
                                                    float* __restrict__ rsq_s,
                                                    float* __restrict__ rsq_t,
                                                    float* __restrict__ rowsum) {
  int b = blockIdx.x;
  int row = b & (N - 1);
  int is_t = b >> 12;
  const float* x = is_t ? xt : xs;
  bf16* y = is_t ? yt : ys;
  float* rowsq = is_t ? rsq_t : rsq_s;
  int tid = threadIdx.x;
  const float* xr = x + (size_t)row * D;
  float v0 = xr[tid], v1 = xr[tid + 256];
  float ss = v0 * v0 + v1 * v1;
  __shared__ float red[4];
  for (int off = 32; off > 0; off >>= 1) ss += __shfl_down(ss, off, 64);
  if ((tid & 63) == 0) red[tid >> 6] = ss;
  __syncthreads();
  float tot = red[0] + red[1] + red[2] + red[3];
  float inv = 1.0f / fmaxf(sqrtf(tot), 1e-12f);
  bf16 b0 = (bf16)(v0 * inv), b1 = (bf16)(v1 * inv);
  bf16* yr = y + (size_t)row * D;
  yr[tid] = b0; yr[tid + 256] = b1;
  float f0 = (float)b0, f1 = (float)b1;
  float s2 = f0 * f0 + f1 * f1;
  for (int off = 32; off > 0; off >>= 1) s2 += __shfl_down(s2, off, 64);
  __syncthreads();
  if ((tid & 63) == 0) red[tid >> 6] = s2;
  __syncthreads();
  if (tid == 0) {
    rowsq[row] = red[0] + red[1] + red[2] + red[3];
    if (!is_t) rowsum[row] = 0.f;
  }
}

// ---------------- Gram: triangular BK=64 K-loop + mirrored epilogue ----------------
// blockIdx.y: 0 = S-gram (sd + rowsum), 1 = T-gram (wp). Triangular map by<=bx.
// Direct store covers rows i (by-panel); off-diag blocks mirror G[j][i] via LDS transpose.
__global__ __launch_bounds__(256) void k_dgram3(const bf16* __restrict__ S,
                                                const bf16* __restrict__ T,
                                                const float* __restrict__ rsq_s,
                                                const float* __restrict__ rsq_t,
                                                f16* __restrict__ Gsd,
                                                f16* __restrict__ Gwp,
                                                float* __restrict__ rowsum) {
  __shared__ __align__(16) char sm[128 * 136 * 2];   // 34816 B: staging (32K) / transpose union
  bf16* Jb0 = (bf16*)sm;
  bf16* Jb1 = (bf16*)(sm + 8192);
  bf16* Ib0 = (bf16*)(sm + 16384);
  bf16* Ib1 = (bf16*)(sm + 24576);
  f16* tp = (f16*)sm;                                // [128][136] padded transpose tile

  int z = blockIdx.y;
  const bf16* Y = z ? T : S;
  const float* rsq = z ? rsq_t : rsq_s;
  f16* G = z ? Gwp : Gsd;

  int t = blockIdx.x, by = 0;
  while (t >= NT - by) { t -= NT - by; ++by; }
  int bx = by + t;
  bool offdiag = (bx != by);

  int tid = threadIdx.x;
  int lane = tid & 63, w = tid >> 6;
  int wr = w >> 1, wc = w & 1;
  int quad = lane >> 4, c = lane & 15;

  const char* Jbase = (const char*)(Y + (size_t)(bx * 128) * D);
  const char* Ibase = (const char*)(Y + (size_t)(by * 128) * D);
  int r0 = tid >> 2, q0 = tid & 3;
  int r1 = (tid + 256) >> 2, q1 = (tid + 256) & 3;
  size_t so0 = (size_t)r0 * (D * 2) + q0 * 16;
  size_t so1 = (size_t)r1 * (D * 2) + q1 * 16;
  bf16* lJ0a = Jb0 + (size_t)w * 512;  bf16* lJ0b = Jb0 + (size_t)(256 + w * 64) * 8;
  bf16* lJ1a = Jb1 + (size_t)w * 512;  bf16* lJ1b = Jb1 + (size_t)(256 + w * 64) * 8;
  bf16* lI0a = Ib0 + (size_t)w * 512;  bf16* lI0b = Ib0 + (size_t)(256 + w * 64) * 8;
  bf16* lI1a = Ib1 + (size_t)w * 512;  bf16* lI1b = Ib1 + (size_t)(256 + w * 64) * 8;

  int jrow = wr * 64 + c;
  int irow = wc * 64 + c;
  int kq = quad * 8;

  f32x4 acc[4][4] = {};
  for (int k0 = 0; k0 < D; k0 += 64) {
    size_t kb = (size_t)k0 * 2;
    gl_lds16(Jbase + so0 + kb,      lJ0a);
    gl_lds16(Jbase + so1 + kb,      lJ0b);
    gl_lds16(Jbase + so0 + kb + 64, lJ1a);
    gl_lds16(Jbase + so1 + kb + 64, lJ1b);
    gl_lds16(Ibase + so0 + kb,      lI0a);
    gl_lds16(Ibase + so1 + kb,      lI0b);
    gl_lds16(Ibase + so0 + kb + 64, lI1a);
    gl_lds16(Ibase + so1 + kb + 64, lI1b);
    __syncthreads();
    {
      bf16x8 af[4], bfr[4];
#pragma unroll
      for (int u = 0; u < 4; ++u) af[u] = *(bf16x8*)&Jb0[(jrow + u * 16) * 32 + kq];
#pragma unroll
      for (int v = 0; v < 4; ++v) bfr[v] = *(bf16x8*)&Ib0[(irow + v * 16) * 32 + kq];
#pragma unroll
      for (int u = 0; u < 4; ++u)
#pragma unroll
        for (int v = 0; v < 4; ++v)
          acc[u][v] = __builtin_amdgcn_mfma_f32_16x16x32_bf16(af[u], bfr[v], acc[u][v], 0, 0, 0);
    }
    {
      bf16x8 af[4], bfr[4];
#pragma unroll
      for (int u = 0; u < 4; ++u) af[u] = *(bf16x8*)&Jb1[(jrow + u * 16) * 32 + kq];
#pragma unroll
      for (int v = 0; v < 4; ++v) bfr[v] = *(bf16x8*)&Ib1[(irow + v * 16) * 32 + kq];
#pragma unroll
      for (int u = 0; u < 4; ++u)
#pragma unroll
        for (int v = 0; v < 4; ++v)
          acc[u][v] = __builtin_amdgcn_mfma_f32_16x16x32_bf16(af[u], bfr[v], acc[u][v], 0, 0, 0);
    }
    __syncthreads();
  }

  // direct store G[i][j] (+ transpose-tile write for off-diag)
#pragma unroll
  for (int v = 0; v < 4; ++v) {
    int il = wc * 64 + v * 16 + c;
    int ig = by * 128 + il;
    float ri = rsq[ig];
    float rsv = 0.f;
#pragma unroll
    for (int u = 0; u < 4; ++u) {
      int jl0 = wr * 64 + u * 16 + quad * 4;
      int jb0i = bx * 128 + jl0;
      float4 rj = *(const float4*)(rsq + jb0i);
      const float* rjp = (const float*)&rj;
      f32x4 a = acc[u][v];
      f16x4 st;
      if (z == 0) {
#pragma unroll
        for (int reg = 0; reg < 4; ++reg) {
          float sq = fmaxf(ri + rjp[reg] - 2.0f * a[reg], 0.0f);
          float val = sqrtf(sq);
          st[reg] = (_Float16)val;
          rsv += val;
        }
      } else {
#pragma unroll
        for (int reg = 0; reg < 4; ++reg) {
          float sq = fmaxf(ri + rjp[reg] - 2.0f * a[reg], 0.0f);
          st[reg] = (_Float16)expf(-sq);
        }
      }
      *(f16x4*)(G + (size_t)ig * N + jb0i) = st;
      if (offdiag) {
#pragma unroll
        for (int reg = 0; reg < 4; ++reg) tp[(jl0 + reg) * 136 + il] = st[reg];
      }
    }
    if (z == 0) {
      rsv += __shfl_xor(rsv, 16, 64);
      rsv += __shfl_xor(rsv, 32, 64);
      if (lane < 16) atomicAdd(&rowsum[ig], rsv);
    }
  }

  // mirrored store G[j][i] from the transpose tile (+ col-sums for z==0)
  if (offdiag) {
    __syncthreads();
    int row2 = tid >> 1, half = tid & 1;
    int jg = bx * 128 + row2;
    size_t gb = (size_t)jg * N + by * 128 + half * 64;
    float csum = 0.f;
#pragma unroll
    for (int k = 0; k < 8; ++k) {
      f16x8 v8 = *(f16x8*)&tp[row2 * 136 + half * 64 + k * 8];
      *(f16x8*)(G + gb + k * 8) = v8;
      if (z == 0) {
#pragma unroll
        for (int e = 0; e < 8; ++e) csum += (float)v8[e];
      }
    }
    if (z == 0) {
      csum += __shfl_down(csum, 1, 64);
      if ((tid & 1) == 0) atomicAdd(&rowsum[jg], csum);
    }
  }
}

// ---------------- Row pass: top-10 (u32 keys) + dense loss ----------------
__global__ __launch_bounds__(256) void k_rowpass(const f16* __restrict__ Gs,
                                                 const f16* __restrict__ Gw,
                                                 const int* __restrict__ ids,
                                                 const float* __restrict__ rowsum,
                                                 int* __restrict__ topk,
                                                 double* __restrict__ pd) {
  __shared__ u32 lds[256 * TOPK];  // 10 KB
  __shared__ double dred[4];
  int i = blockIdx.x, tid = threadIdx.x;
  int idi = ids[i];
  float invm = 1.0f / (rowsum[i] * INV_N);
  const u16* srow = (const u16*)(Gs + (size_t)i * N);
  const u16* wrow = (const u16*)(Gw + (size_t)i * N);
  u32 top[TOPK];
#pragma unroll
  for (int o = 0; o < TOPK; ++o) top[o] = 0u;
  float dsum = 0.f;
  int j0 = tid * 16;
#pragma unroll
  for (int h = 0; h < 2; ++h) {
    int jb = j0 + h * 8;
    u16x8 sv = *(const u16x8*)(srow + jb);
    u16x8 wv = *(const u16x8*)(wrow + jb);
    int4 id0 = *(const int4*)(ids + jb);
    int4 id1 = *(const int4*)(ids + jb + 4);
    const int* idp = (const int*)&id0;
    const int* idp1 = (const int*)&id1;
#pragma unroll
    for (int e = 0; e < 8; ++e) {
      int j = jb + e;
      u16 hw = wv[e];
      float wp = f16tof(hw);
      if (j != i) {
        float sdn = f16tof(sv[e]) * invm;
        float r = fmaxf(1.0f - sdn, 0.0f); r *= r;
        dsum += r + 0.5f * wp * (sdn * sdn - r);
      }
      int idj = (e < 4) ? idp[e] : idp1[e - 4];
      u16 hk = (idj == idi) ? (u16)0x3C00 : hw;
      u32 key = ((u32)hk << 16) | (u32)(4095 - j);
      if (key > top[TOPK - 1]) {
        top[TOPK - 1] = key;
#pragma unroll
        for (int a = TOPK - 2; a >= 0; --a)
          if (top[a + 1] > top[a]) { u32 t = top[a]; top[a] = top[a + 1]; top[a + 1] = t; }
      }
    }
  }
  double dl = (double)dsum;
  for (int off = 32; off > 0; off >>= 1) dl += __shfl_down(dl, off, 64);
  if ((tid & 63) == 0) dred[tid >> 6] = dl;
#pragma unroll
  for (int o = 0; o < TOPK; ++o) lds[tid * TOPK + o] = top[o];
  __syncthreads();
  for (int off = 128; off >= 1; off >>= 1) {
    if (tid < off) {
      u32 out[TOPK];
      int pa = 0, pb = 0;
#pragma unroll
      for (int o = 0; o < TOPK; ++o) {
        u32 ka = lds[tid * TOPK + pa];
        u32 kb = lds[(tid + off) * TOPK + pb];
        bool ta = ka >= kb;
        out[o] = ta ? ka : kb;
        pa += ta ? 1 : 0;
        pb += ta ? 0 : 1;
      }
#pragma unroll
      for (int o = 0; o < TOPK; ++o) lds[tid * TOPK + o] = out[o];
    }
    __syncthreads();
  }
  if (tid == 0) {
#pragma unroll
    for (int o = 0; o < TOPK; ++o)
      topk[i * TOPK + o] = 4095 - (int)(lds[o] & 0xFFFu);
    pd[i] = dred[0] + dred[1] + dred[2] + dred[3];
  }
}

// ---------------- mutual-kNN lists ----------------
__global__ void k_buildV(const int* __restrict__ topk, int* __restrict__ L,
                         int* __restrict__ cnt) {
  int i = blockIdx.x * 256 + threadIdx.x;
  if (i >= N) return;
  int c = 0;
  for (int r = 0; r < TOPK; ++r) {
    int j = topk[i * TOPK + r];
    bool mut = false;
    for (int q = 0; q < TOPK; ++q) mut |= (topk[j * TOPK + q] == i);
    if (mut) L[i * TOPK + c++] = j;
  }
  cnt[i] = c;
}

// ---------------- sparse W_C loss, one wave per task ----------------
__global__ __launch_bounds__(256) void k_wc(const int* __restrict__ topk,
                                            const int* __restrict__ L,
                                            const int* __restrict__ cnt,
                                            const bf16* __restrict__ S,
                                            const float* __restrict__ rsq,
                                            const float* __restrict__ rowsum,
                                            double* __restrict__ pw) {
  int tid = threadIdx.x;
  int lane = tid & 63;
  int wv = tid >> 6;
  int task = blockIdx.x * 4 + wv;
  int i = task / TOPK_HALF, m = task % TOPK_HALF;
  int r = topk[i * TOPK + m];
  int cr = cnt[r];
  double local = 0.0;
  if (cr > 0) {
    float denom = (float)(cr > 1 ? cr : 1);
    int lval = (lane < cr) ? L[r * TOPK + lane] : -1;
    int Lr[TOPK];
#pragma unroll
    for (int a = 0; a < TOPK; ++a) Lr[a] = __shfl(lval, a, 64);
    float invmi = 1.0f / (rowsum[i] * INV_N);
    float rsqi = rsq[i];
    bf16x8 vi = *(const bf16x8*)(S + (size_t)i * D + lane * 8);
    float fi[8];
#pragma unroll
    for (int k = 0; k < 8; ++k) fi[k] = (float)vi[k];
    int cj_l = 0; float mj_l = 1.0f;
    if (lane < cr) { cj_l = cnt[lval]; mj_l = rowsum[lval] * INV_N; }
    for (int jj = 0; jj < cr; ++jj) {
      int j = Lr[jj];
      if (j == i) continue;
      int cj = __shfl(cj_l, jj, 64);
      float mj = __shfl(mj_l, jj, 64);
      bf16x8 vj = *(const bf16x8*)(S + (size_t)j * D + lane * 8);
      float dot = 0.f;
#pragma unroll
      for (int k = 0; k < 8; ++k) dot = fmaf(fi[k], (float)vj[k], dot);
#pragma unroll
      for (int off = 32; off > 0; off >>= 1) dot += __shfl_xor(dot, off, 64);
      float sq = fmaxf(rsqi + rsq[j] - 2.0f * dot, 0.0f);
      float sr_ = sqrtf(sq);
      int ljb = (lane < cj) ? L[j * TOPK + lane] : -1;
      int match = 0;
#pragma unroll
      for (int a = 0; a < TOPK; ++a) match |= ((a < cr) && (ljb == Lr[a])) ? 1 : 0;
      int vv = __popcll(__ballot(match != 0));
      float wgt = (float)vv / denom;
      float sdij = sr_ * invmi;
      float sdji = sr_ / mj;
      float Rij = fmaxf(1.0f - sdij, 0.0f); Rij *= Rij;
      float Rji = fmaxf(1.0f - sdji, 0.0f); Rji *= Rji;
      float Fij = sdij * sdij - Rij;
      float Fji = sdji * sdji - Rji;
      local += (double)(wgt * (Fij + Fji));
    }
    local *= (1.0 / 20.0);
  }
  __shared__ double red[4];
  if (lane == 0) red[wv] = local;
  __syncthreads();
  if (tid == 0) pw[blockIdx.x] = red[0] + red[1] + red[2] + red[3];
}

// ---------------- final reduce ----------------
__global__ __launch_bounds__(256) void k_final(const double* __restrict__ pd,
                                               const double* __restrict__ pw,
                                               float* __restrict__ out) {
  int tid = threadIdx.x;
  double s = 0.0;
  for (int i = tid; i < N; i += 256) s += pd[i];
  for (int i = tid; i < WC_BLOCKS; i += 256) s += pw[i];
  for (int off = 32; off > 0; off >>= 1) s += __shfl_down(s, off, 64);
  __shared__ double red[4];
  if ((tid & 63) == 0) red[tid >> 6] = s;
  __syncthreads();
  if (tid == 0)
    out[0] = (float)((red[0] + red[1] + red[2] + red[3]) /
                     ((double)N * (double)(N - 1)));
}

extern "C" void kernel_launch(void* const* d_in, const int* in_sizes, int n_in,
                              void* d_out, int out_size, void* d_ws, size_t ws_size,
                              hipStream_t stream) {
  const float* s_emb = (const float*)d_in[0];
  const float* t_emb = (const float*)d_in[1];
  const int* ids = (const int*)d_in[2];
  float* out = (float*)d_out;

  char* ws = (char*)d_ws;
  size_t off = 0;
  bf16* snorm = (bf16*)(ws + off); off += (size_t)N * D * 2;        // 4 MB
  bf16* tnorm = (bf16*)(ws + off); off += (size_t)N * D * 2;        // 4 MB
  f16*  Gsd   = (f16*)(ws + off);  off += (size_t)N * N * 2;        // 32 MB
  f16*  Gwp   = (f16*)(ws + off);  off += (size_t)N * N * 2;        // 32 MB
  float* rsq_s = (float*)(ws + off); off += (size_t)N * 4;
  float* rsq_t = (float*)(ws + off); off += (size_t)N * 4;
  float* rowsum= (float*)(ws + off); off += (size_t)N * 4;
  int*   topk  = (int*)(ws + off);   off += (size_t)N * TOPK * 4;
  int*   L     = (int*)(ws + off);   off += (size_t)N * TOPK * 4;
  int*   cnt   = (int*)(ws + off);   off += (size_t)N * 4;
  off = (off + 15) & ~(size_t)15;
  double* pd   = (double*)(ws + off); off += (size_t)N * 8;
  double* pw   = (double*)(ws + off); off += (size_t)WC_BLOCKS * 8;

  k_normalize2<<<2 * N, 256, 0, stream>>>(s_emb, t_emb, snorm, tnorm,
                                          rsq_s, rsq_t, rowsum);
  k_dgram3<<<dim3(TRI_BLOCKS, 2), 256, 0, stream>>>(snorm, tnorm, rsq_s, rsq_t,
                                                    Gsd, Gwp, rowsum);
  k_rowpass<<<N, 256, 0, stream>>>(Gsd, Gwp, ids, rowsum, topk, pd);
  k_buildV<<<N / 256, 256, 0, stream>>>(topk, L, cnt);
  k_wc<<<WC_BLOCKS, 256, 0, stream>>>(topk, L, cnt, snorm, rsq_s, rowsum, pw);
  k_final<<<1, 256, 0, stream>>>(pd, pw, out);
}

// Round 11
// 201.171 us; speedup vs baseline: 1.0535x; 1.0535x over previous
//
#include <hip/hip_runtime.h>
#include <math.h>

#define N 4096
#define D 512
#define TOPK 10
#define TOPK_HALF 5
#define NT 32
#define TRI_BLOCKS (NT * (NT + 1) / 2)   // 528
#define WC_BLOCKS (N * TOPK_HALF / 4)
#define INV_N (1.0f / 4096.0f)

typedef __bf16 bf16;
typedef __bf16 bf16x8 __attribute__((ext_vector_type(8)));
typedef float f32x4 __attribute__((ext_vector_type(4)));
typedef _Float16 f16;
typedef _Float16 f16x4 __attribute__((ext_vector_type(4)));
typedef _Float16 f16x8 __attribute__((ext_vector_type(8)));
typedef unsigned short u16;
typedef unsigned short u16x8 __attribute__((ext_vector_type(8)));
typedef unsigned int u32;

__device__ __forceinline__ void gl_lds16(const void* g, void* l) {
  __builtin_amdgcn_global_load_lds(
      (const __attribute__((address_space(1))) void*)g,
      (__attribute__((address_space(3))) void*)l, 16, 0, 0);
}

__device__ __forceinline__ float f16tof(u16 h) {
  return (float)__builtin_bit_cast(_Float16, h);
}

// ---------------- K0: L2-normalize both matrices ----------------
__global__ __launch_bounds__(256) void k_normalize2(const float* __restrict__ xs,
                                                    const float* __restrict__ xt,
                                                    bf16* __restrict__ ys,
                                                    bf16* __restrict__ yt,
                                                    float* __restrict__ rsq_s,
                                                    float* __restrict__ rsq_t,
                                                    float* __restrict__ rowsum) {
  int b = blockIdx.x;
  int row = b & (N - 1);
  int is_t = b >> 12;
  const float* x = is_t ? xt : xs;
  bf16* y = is_t ? yt : ys;
  float* rowsq = is_t ? rsq_t : rsq_s;
  int tid = threadIdx.x;
  const float* xr = x + (size_t)row * D;
  float v0 = xr[tid], v1 = xr[tid + 256];
  float ss = v0 * v0 + v1 * v1;
  __shared__ float red[4];
  for (int off = 32; off > 0; off >>= 1) ss += __shfl_down(ss, off, 64);
  if ((tid & 63) == 0) red[tid >> 6] = ss;
  __syncthreads();
  float tot = red[0] + red[1] + red[2] + red[3];
  float inv = 1.0f / fmaxf(sqrtf(tot), 1e-12f);
  bf16 b0 = (bf16)(v0 * inv), b1 = (bf16)(v1 * inv);
  bf16* yr = y + (size_t)row * D;
  yr[tid] = b0; yr[tid + 256] = b1;
  float f0 = (float)b0, f1 = (float)b1;
  float s2 = f0 * f0 + f1 * f1;
  for (int off = 32; off > 0; off >>= 1) s2 += __shfl_down(s2, off, 64);
  __syncthreads();
  if ((tid & 63) == 0) red[tid >> 6] = s2;
  __syncthreads();
  if (tid == 0) {
    rowsq[row] = red[0] + red[1] + red[2] + red[3];
    if (!is_t) rowsum[row] = 0.f;
  }
}

// ---------------- Gram: triangular BK=64 K-loop + coalesced mirrored epilogue ----------------
// blockIdx.y: 0 = S-gram (sd + rowsum), 1 = T-gram (wp). Triangular map by<=bx.
__global__ __launch_bounds__(256) void k_dgram3(const bf16* __restrict__ S,
                                                const bf16* __restrict__ T,
                                                const float* __restrict__ rsq_s,
                                                const float* __restrict__ rsq_t,
                                                f16* __restrict__ Gsd,
                                                f16* __restrict__ Gwp,
                                                float* __restrict__ rowsum) {
  __shared__ __align__(16) char sm[128 * 136 * 2];   // 34816 B: staging (32K) / transpose union
  bf16* Jb0 = (bf16*)sm;
  bf16* Jb1 = (bf16*)(sm + 8192);
  bf16* Ib0 = (bf16*)(sm + 16384);
  bf16* Ib1 = (bf16*)(sm + 24576);
  f16* tp = (f16*)sm;                                // [128][136] padded transpose tile

  int z = blockIdx.y;
  const bf16* Y = z ? T : S;
  const float* rsq = z ? rsq_t : rsq_s;
  f16* G = z ? Gwp : Gsd;

  int t = blockIdx.x, by = 0;
  while (t >= NT - by) { t -= NT - by; ++by; }
  int bx = by + t;
  bool offdiag = (bx != by);

  int tid = threadIdx.x;
  int lane = tid & 63, w = tid >> 6;
  int wr = w >> 1, wc = w & 1;
  int quad = lane >> 4, c = lane & 15;

  const char* Jbase = (const char*)(Y + (size_t)(bx * 128) * D);
  const char* Ibase = (const char*)(Y + (size_t)(by * 128) * D);
  int r0 = tid >> 2, q0 = tid & 3;
  int r1 = (tid + 256) >> 2, q1 = (tid + 256) & 3;
  size_t so0 = (size_t)r0 * (D * 2) + q0 * 16;
  size_t so1 = (size_t)r1 * (D * 2) + q1 * 16;
  bf16* lJ0a = Jb0 + (size_t)w * 512;  bf16* lJ0b = Jb0 + (size_t)(256 + w * 64) * 8;
  bf16* lJ1a = Jb1 + (size_t)w * 512;  bf16* lJ1b = Jb1 + (size_t)(256 + w * 64) * 8;
  bf16* lI0a = Ib0 + (size_t)w * 512;  bf16* lI0b = Ib0 + (size_t)(256 + w * 64) * 8;
  bf16* lI1a = Ib1 + (size_t)w * 512;  bf16* lI1b = Ib1 + (size_t)(256 + w * 64) * 8;

  int jrow = wr * 64 + c;
  int irow = wc * 64 + c;
  int kq = quad * 8;

  f32x4 acc[4][4] = {};
  for (int k0 = 0; k0 < D; k0 += 64) {
    size_t kb = (size_t)k0 * 2;
    gl_lds16(Jbase + so0 + kb,      lJ0a);
    gl_lds16(Jbase + so1 + kb,      lJ0b);
    gl_lds16(Jbase + so0 + kb + 64, lJ1a);
    gl_lds16(Jbase + so1 + kb + 64, lJ1b);
    gl_lds16(Ibase + so0 + kb,      lI0a);
    gl_lds16(Ibase + so1 + kb,      lI0b);
    gl_lds16(Ibase + so0 + kb + 64, lI1a);
    gl_lds16(Ibase + so1 + kb + 64, lI1b);
    __syncthreads();
    {
      bf16x8 af[4], bfr[4];
#pragma unroll
      for (int u = 0; u < 4; ++u) af[u] = *(bf16x8*)&Jb0[(jrow + u * 16) * 32 + kq];
#pragma unroll
      for (int v = 0; v < 4; ++v) bfr[v] = *(bf16x8*)&Ib0[(irow + v * 16) * 32 + kq];
#pragma unroll
      for (int u = 0; u < 4; ++u)
#pragma unroll
        for (int v = 0; v < 4; ++v)
          acc[u][v] = __builtin_amdgcn_mfma_f32_16x16x32_bf16(af[u], bfr[v], acc[u][v], 0, 0, 0);
    }
    {
      bf16x8 af[4], bfr[4];
#pragma unroll
      for (int u = 0; u < 4; ++u) af[u] = *(bf16x8*)&Jb1[(jrow + u * 16) * 32 + kq];
#pragma unroll
      for (int v = 0; v < 4; ++v) bfr[v] = *(bf16x8*)&Ib1[(irow + v * 16) * 32 + kq];
#pragma unroll
      for (int u = 0; u < 4; ++u)
#pragma unroll
        for (int v = 0; v < 4; ++v)
          acc[u][v] = __builtin_amdgcn_mfma_f32_16x16x32_bf16(af[u], bfr[v], acc[u][v], 0, 0, 0);
    }
    __syncthreads();
  }

  // direct store G[i][j] (+ transpose-tile write for off-diag)
#pragma unroll
  for (int v = 0; v < 4; ++v) {
    int il = wc * 64 + v * 16 + c;
    int ig = by * 128 + il;
    float ri = rsq[ig];
    float rsv = 0.f;
#pragma unroll
    for (int u = 0; u < 4; ++u) {
      int jl0 = wr * 64 + u * 16 + quad * 4;
      int jb0i = bx * 128 + jl0;
      float4 rj = *(const float4*)(rsq + jb0i);
      const float* rjp = (const float*)&rj;
      f32x4 a = acc[u][v];
      f16x4 st;
      if (z == 0) {
#pragma unroll
        for (int reg = 0; reg < 4; ++reg) {
          float sq = fmaxf(ri + rjp[reg] - 2.0f * a[reg], 0.0f);
          float val = sqrtf(sq);
          st[reg] = (_Float16)val;
          rsv += val;
        }
      } else {
#pragma unroll
        for (int reg = 0; reg < 4; ++reg) {
          float sq = fmaxf(ri + rjp[reg] - 2.0f * a[reg], 0.0f);
          st[reg] = (_Float16)expf(-sq);
        }
      }
      *(f16x4*)(G + (size_t)ig * N + jb0i) = st;
      if (offdiag) {
#pragma unroll
        for (int reg = 0; reg < 4; ++reg) tp[(jl0 + reg) * 136 + il] = st[reg];
      }
    }
    if (z == 0) {
      rsv += __shfl_xor(rsv, 16, 64);
      rsv += __shfl_xor(rsv, 32, 64);
      if (lane < 16) atomicAdd(&rowsum[ig], rsv);
    }
  }

  // mirrored store G[j][i]: 16 lanes/row, 256 B contiguous per row -> full-line writes
  if (offdiag) {
    __syncthreads();
    int rloc = tid >> 4;        // 0..15
    int cseg = tid & 15;        // 16-byte segment within the 256 B row span
#pragma unroll
    for (int it = 0; it < 8; ++it) {
      int jl = it * 16 + rloc;
      int jg = bx * 128 + jl;
      f16x8 v8 = *(f16x8*)&tp[jl * 136 + cseg * 8];
      *(f16x8*)(G + (size_t)jg * N + by * 128 + cseg * 8) = v8;
      if (z == 0) {
        float csum = 0.f;
#pragma unroll
        for (int e = 0; e < 8; ++e) csum += (float)v8[e];
        csum += __shfl_xor(csum, 1, 64);
        csum += __shfl_xor(csum, 2, 64);
        csum += __shfl_xor(csum, 4, 64);
        csum += __shfl_xor(csum, 8, 64);
        if (cseg == 0) atomicAdd(&rowsum[jg], csum);
      }
    }
  }
}

// ---------------- Row pass: top-10 (u32 keys) + dense loss ----------------
__global__ __launch_bounds__(256) void k_rowpass(const f16* __restrict__ Gs,
                                                 const f16* __restrict__ Gw,
                                                 const int* __restrict__ ids,
                                                 const float* __restrict__ rowsum,
                                                 int* __restrict__ topk,
                                                 double* __restrict__ pd) {
  __shared__ u32 lds[256 * TOPK];  // 10 KB
  __shared__ double dred[4];
  int i = blockIdx.x, tid = threadIdx.x;
  int idi = ids[i];
  float invm = 1.0f / (rowsum[i] * INV_N);
  const u16* srow = (const u16*)(Gs + (size_t)i * N);
  const u16* wrow = (const u16*)(Gw + (size_t)i * N);
  u32 top[TOPK];
#pragma unroll
  for (int o = 0; o < TOPK; ++o) top[o] = 0u;
  float dsum = 0.f;
  int j0 = tid * 16;
#pragma unroll
  for (int h = 0; h < 2; ++h) {
    int jb = j0 + h * 8;
    u16x8 sv = *(const u16x8*)(srow + jb);
    u16x8 wv = *(const u16x8*)(wrow + jb);
    int4 id0 = *(const int4*)(ids + jb);
    int4 id1 = *(const int4*)(ids + jb + 4);
    const int* idp = (const int*)&id0;
    const int* idp1 = (const int*)&id1;
#pragma unroll
    for (int e = 0; e < 8; ++e) {
      int j = jb + e;
      u16 hw = wv[e];
      float wp = f16tof(hw);
      if (j != i) {
        float sdn = f16tof(sv[e]) * invm;
        float r = fmaxf(1.0f - sdn, 0.0f); r *= r;
        dsum += r + 0.5f * wp * (sdn * sdn - r);
      }
      int idj = (e < 4) ? idp[e] : idp1[e - 4];
      u16 hk = (idj == idi) ? (u16)0x3C00 : hw;
      u32 key = ((u32)hk << 16) | (u32)(4095 - j);
      if (key > top[TOPK - 1]) {
        top[TOPK - 1] = key;
#pragma unroll
        for (int a = TOPK - 2; a >= 0; --a)
          if (top[a + 1] > top[a]) { u32 t = top[a]; top[a] = top[a + 1]; top[a + 1] = t; }
      }
    }
  }
  double dl = (double)dsum;
  for (int off = 32; off > 0; off >>= 1) dl += __shfl_down(dl, off, 64);
  if ((tid & 63) == 0) dred[tid >> 6] = dl;
#pragma unroll
  for (int o = 0; o < TOPK; ++o) lds[tid * TOPK + o] = top[o];
  __syncthreads();
  for (int off = 128; off >= 1; off >>= 1) {
    if (tid < off) {
      u32 out[TOPK];
      int pa = 0, pb = 0;
#pragma unroll
      for (int o = 0; o < TOPK; ++o) {
        u32 ka = lds[tid * TOPK + pa];
        u32 kb = lds[(tid + off) * TOPK + pb];
        bool ta = ka >= kb;
        out[o] = ta ? ka : kb;
        pa += ta ? 1 : 0;
        pb += ta ? 0 : 1;
      }
#pragma unroll
      for (int o = 0; o < TOPK; ++o) lds[tid * TOPK + o] = out[o];
    }
    __syncthreads();
  }
  if (tid == 0) {
#pragma unroll
    for (int o = 0; o < TOPK; ++o)
      topk[i * TOPK + o] = 4095 - (int)(lds[o] & 0xFFFu);
    pd[i] = dred[0] + dred[1] + dred[2] + dred[3];
  }
}

// ---------------- mutual-kNN lists ----------------
__global__ void k_buildV(const int* __restrict__ topk, int* __restrict__ L,
                         int* __restrict__ cnt) {
  int i = blockIdx.x * 256 + threadIdx.x;
  if (i >= N) return;
  int c = 0;
  for (int r = 0; r < TOPK; ++r) {
    int j = topk[i * TOPK + r];
    bool mut = false;
    for (int q = 0; q < TOPK; ++q) mut |= (topk[j * TOPK + q] == i);
    if (mut) L[i * TOPK + c++] = j;
  }
  cnt[i] = c;
}

// ---------------- sparse W_C loss, one wave per task ----------------
__global__ __launch_bounds__(256) void k_wc(const int* __restrict__ topk,
                                            const int* __restrict__ L,
                                            const int* __restrict__ cnt,
                                            const bf16* __restrict__ S,
                                            const float* __restrict__ rsq,
                                            const float* __restrict__ rowsum,
                                            double* __restrict__ pw) {
  int tid = threadIdx.x;
  int lane = tid & 63;
  int wv = tid >> 6;
  int task = blockIdx.x * 4 + wv;
  int i = task / TOPK_HALF, m = task % TOPK_HALF;
  int r = topk[i * TOPK + m];
  int cr = cnt[r];
  double local = 0.0;
  if (cr > 0) {
    float denom = (float)(cr > 1 ? cr : 1);
    int lval = (lane < cr) ? L[r * TOPK + lane] : -1;
    int Lr[TOPK];
#pragma unroll
    for (int a = 0; a < TOPK; ++a) Lr[a] = __shfl(lval, a, 64);
    float invmi = 1.0f / (rowsum[i] * INV_N);
    float rsqi = rsq[i];
    bf16x8 vi = *(const bf16x8*)(S + (size_t)i * D + lane * 8);
    float fi[8];
#pragma unroll
    for (int k = 0; k < 8; ++k) fi[k] = (float)vi[k];
    int cj_l = 0; float mj_l = 1.0f;
    if (lane < cr) { cj_l = cnt[lval]; mj_l = rowsum[lval] * INV_N; }
    for (int jj = 0; jj < cr; ++jj) {
      int j = Lr[jj];
      if (j == i) continue;
      int cj = __shfl(cj_l, jj, 64);
      float mj = __shfl(mj_l, jj, 64);
      bf16x8 vj = *(const bf16x8*)(S + (size_t)j * D + lane * 8);
      float dot = 0.f;
#pragma unroll
      for (int k = 0; k < 8; ++k) dot = fmaf(fi[k], (float)vj[k], dot);
#pragma unroll
      for (int off = 32; off > 0; off >>= 1) dot += __shfl_xor(dot, off, 64);
      float sq = fmaxf(rsqi + rsq[j] - 2.0f * dot, 0.0f);
      float sr_ = sqrtf(sq);
      int ljb = (lane < cj) ? L[j * TOPK + lane] : -1;
      int match = 0;
#pragma unroll
      for (int a = 0; a < TOPK; ++a) match |= ((a < cr) && (ljb == Lr[a])) ? 1 : 0;
      int vv = __popcll(__ballot(match != 0));
      float wgt = (float)vv / denom;
      float sdij = sr_ * invmi;
      float sdji = sr_ / mj;
      float Rij = fmaxf(1.0f - sdij, 0.0f); Rij *= Rij;
      float Rji = fmaxf(1.0f - sdji, 0.0f); Rji *= Rji;
      float Fij = sdij * sdij - Rij;
      float Fji = sdji * sdji - Rji;
      local += (double)(wgt * (Fij + Fji));
    }
    local *= (1.0 / 20.0);
  }
  __shared__ double red[4];
  if (lane == 0) red[wv] = local;
  __syncthreads();
  if (tid == 0) pw[blockIdx.x] = red[0] + red[1] + red[2] + red[3];
}

// ---------------- final reduce ----------------
__global__ __launch_bounds__(256) void k_final(const double* __restrict__ pd,
                                               const double* __restrict__ pw,
                                               float* __restrict__ out) {
  int tid = threadIdx.x;
  double s = 0.0;
  for (int i = tid; i < N; i += 256) s += pd[i];
  for (int i = tid; i < WC_BLOCKS; i += 256) s += pw[i];
  for (int off = 32; off > 0; off >>= 1) s += __shfl_down(s, off, 64);
  __shared__ double red[4];
  if ((tid & 63) == 0) red[tid >> 6] = s;
  __syncthreads();
  if (tid == 0)
    out[0] = (float)((red[0] + red[1] + red[2] + red[3]) /
                     ((double)N * (double)(N - 1)));
}

extern "C" void kernel_launch(void* const* d_in, const int* in_sizes, int n_in,
                              void* d_out, int out_size, void* d_ws, size_t ws_size,
                              hipStream_t stream) {
  const float* s_emb = (const float*)d_in[0];
  const float* t_emb = (const float*)d_in[1];
  const int* ids = (const int*)d_in[2];
  float* out = (float*)d_out;

  char* ws = (char*)d_ws;
  size_t off = 0;
  bf16* snorm = (bf16*)(ws + off); off += (size_t)N * D * 2;        // 4 MB
  bf16* tnorm = (bf16*)(ws + off); off += (size_t)N * D * 2;        // 4 MB
  f16*  Gsd   = (f16*)(ws + off);  off += (size_t)N * N * 2;        // 32 MB
  f16*  Gwp   = (f16*)(ws + off);  off += (size_t)N * N * 2;        // 32 MB
  float* rsq_s = (float*)(ws + off); off += (size_t)N * 4;
  float* rsq_t = (float*)(ws + off); off += (size_t)N * 4;
  float* rowsum= (float*)(ws + off); off += (size_t)N * 4;
  int*   topk  = (int*)(ws + off);   off += (size_t)N * TOPK * 4;
  int*   L     = (int*)(ws + off);   off += (size_t)N * TOPK * 4;
  int*   cnt   = (int*)(ws + off);   off += (size_t)N * 4;
  off = (off + 15) & ~(size_t)15;
  double* pd   = (double*)(ws + off); off += (size_t)N * 8;
  double* pw   = (double*)(ws + off); off += (size_t)WC_BLOCKS * 8;

  k_normalize2<<<2 * N, 256, 0, stream>>>(s_emb, t_emb, snorm, tnorm,
                                          rsq_s, rsq_t, rowsum);
  k_dgram3<<<dim3(TRI_BLOCKS, 2), 256, 0, stream>>>(snorm, tnorm, rsq_s, rsq_t,
                                                    Gsd, Gwp, rowsum);
  k_rowpass<<<N, 256, 0, stream>>>(Gsd, Gwp, ids, rowsum, topk, pd);
  k_buildV<<<N / 256, 256, 0, stream>>>(topk, L, cnt);
  k_wc<<<WC_BLOCKS, 256, 0, stream>>>(topk, L, cnt, snorm, rsq_s, rowsum, pw);
  k_final<<<1, 256, 0, stream>>>(pd, pw, out);
}

// Round 12
// 196.008 us; speedup vs baseline: 1.0813x; 1.0263x over previous
//
#include <hip/hip_runtime.h>
#include <math.h>

#define N 4096
#define D 512
#define TOPK 10
#define TOPK_HALF 5
#define NT 32
#define TRI_BLOCKS (NT * (NT + 1) / 2)   // 528
#define WC_BLOCKS (N * TOPK_HALF / 4)
#define INV_N (1.0f / 4096.0f)

typedef __bf16 bf16;
typedef __bf16 bf16x8 __attribute__((ext_vector_type(8)));
typedef float f32x4 __attribute__((ext_vector_type(4)));
typedef _Float16 f16;
typedef _Float16 f16x4 __attribute__((ext_vector_type(4)));
typedef _Float16 f16x8 __attribute__((ext_vector_type(8)));
typedef unsigned short u16;
typedef unsigned short u16x8 __attribute__((ext_vector_type(8)));
typedef unsigned int u32;

__device__ __forceinline__ void gl_lds16(const void* g, void* l) {
  __builtin_amdgcn_global_load_lds(
      (const __attribute__((address_space(1))) void*)g,
      (__attribute__((address_space(3))) void*)l, 16, 0, 0);
}

__device__ __forceinline__ float f16tof(u16 h) {
  return (float)__builtin_bit_cast(_Float16, h);
}

// ---------------- K0: L2-normalize both matrices ----------------
__global__ __launch_bounds__(256) void k_normalize2(const float* __restrict__ xs,
                                                    const float* __restrict__ xt,
                                                    bf16* __restrict__ ys,
                                                    bf16* __restrict__ yt,
                                                    float* __restrict__ rsq_s,
                                                    float* __restrict__ rsq_t,
                                                    float* __restrict__ rowsum) {
  int b = blockIdx.x;
  int row = b & (N - 1);
  int is_t = b >> 12;
  const float* x = is_t ? xt : xs;
  bf16* y = is_t ? yt : ys;
  float* rowsq = is_t ? rsq_t : rsq_s;
  int tid = threadIdx.x;
  const float* xr = x + (size_t)row * D;
  float v0 = xr[tid], v1 = xr[tid + 256];
  float ss = v0 * v0 + v1 * v1;
  __shared__ float red[4];
  for (int off = 32; off > 0; off >>= 1) ss += __shfl_down(ss, off, 64);
  if ((tid & 63) == 0) red[tid >> 6] = ss;
  __syncthreads();
  float tot = red[0] + red[1] + red[2] + red[3];
  float inv = 1.0f / fmaxf(sqrtf(tot), 1e-12f);
  bf16 b0 = (bf16)(v0 * inv), b1 = (bf16)(v1 * inv);
  bf16* yr = y + (size_t)row * D;
  yr[tid] = b0; yr[tid + 256] = b1;
  float f0 = (float)b0, f1 = (float)b1;
  float s2 = f0 * f0 + f1 * f1;
  for (int off = 32; off > 0; off >>= 1) s2 += __shfl_down(s2, off, 64);
  __syncthreads();
  if ((tid & 63) == 0) red[tid >> 6] = s2;
  __syncthreads();
  if (tid == 0) {
    rowsq[row] = red[0] + red[1] + red[2] + red[3];
    if (!is_t) rowsum[row] = 0.f;
  }
}

// ---------------- Gram: triangular BK=64 K-loop + coalesced mirrored epilogue ----------------
__global__ __launch_bounds__(256) void k_dgram3(const bf16* __restrict__ S,
                                                const bf16* __restrict__ T,
                                                const float* __restrict__ rsq_s,
                                                const float* __restrict__ rsq_t,
                                                f16* __restrict__ Gsd,
                                                f16* __restrict__ Gwp,
                                                float* __restrict__ rowsum) {
  __shared__ __align__(16) char sm[128 * 136 * 2];   // 34816 B: staging / transpose union
  bf16* Jb0 = (bf16*)sm;
  bf16* Jb1 = (bf16*)(sm + 8192);
  bf16* Ib0 = (bf16*)(sm + 16384);
  bf16* Ib1 = (bf16*)(sm + 24576);
  f16* tp = (f16*)sm;                                // [128][136] padded transpose tile

  int z = blockIdx.y;
  const bf16* Y = z ? T : S;
  const float* rsq = z ? rsq_t : rsq_s;
  f16* G = z ? Gwp : Gsd;

  int t = blockIdx.x, by = 0;
  while (t >= NT - by) { t -= NT - by; ++by; }
  int bx = by + t;
  bool offdiag = (bx != by);

  int tid = threadIdx.x;
  int lane = tid & 63, w = tid >> 6;
  int wr = w >> 1, wc = w & 1;
  int quad = lane >> 4, c = lane & 15;

  const char* Jbase = (const char*)(Y + (size_t)(bx * 128) * D);
  const char* Ibase = (const char*)(Y + (size_t)(by * 128) * D);
  int r0 = tid >> 2, q0 = tid & 3;
  int r1 = (tid + 256) >> 2, q1 = (tid + 256) & 3;
  size_t so0 = (size_t)r0 * (D * 2) + q0 * 16;
  size_t so1 = (size_t)r1 * (D * 2) + q1 * 16;
  bf16* lJ0a = Jb0 + (size_t)w * 512;  bf16* lJ0b = Jb0 + (size_t)(256 + w * 64) * 8;
  bf16* lJ1a = Jb1 + (size_t)w * 512;  bf16* lJ1b = Jb1 + (size_t)(256 + w * 64) * 8;
  bf16* lI0a = Ib0 + (size_t)w * 512;  bf16* lI0b = Ib0 + (size_t)(256 + w * 64) * 8;
  bf16* lI1a = Ib1 + (size_t)w * 512;  bf16* lI1b = Ib1 + (size_t)(256 + w * 64) * 8;

  int jrow = wr * 64 + c;
  int irow = wc * 64 + c;
  int kq = quad * 8;

  f32x4 acc[4][4] = {};
  for (int k0 = 0; k0 < D; k0 += 64) {
    size_t kb = (size_t)k0 * 2;
    gl_lds16(Jbase + so0 + kb,      lJ0a);
    gl_lds16(Jbase + so1 + kb,      lJ0b);
    gl_lds16(Jbase + so0 + kb + 64, lJ1a);
    gl_lds16(Jbase + so1 + kb + 64, lJ1b);
    gl_lds16(Ibase + so0 + kb,      lI0a);
    gl_lds16(Ibase + so1 + kb,      lI0b);
    gl_lds16(Ibase + so0 + kb + 64, lI1a);
    gl_lds16(Ibase + so1 + kb + 64, lI1b);
    __syncthreads();
    {
      bf16x8 af[4], bfr[4];
#pragma unroll
      for (int u = 0; u < 4; ++u) af[u] = *(bf16x8*)&Jb0[(jrow + u * 16) * 32 + kq];
#pragma unroll
      for (int v = 0; v < 4; ++v) bfr[v] = *(bf16x8*)&Ib0[(irow + v * 16) * 32 + kq];
#pragma unroll
      for (int u = 0; u < 4; ++u)
#pragma unroll
        for (int v = 0; v < 4; ++v)
          acc[u][v] = __builtin_amdgcn_mfma_f32_16x16x32_bf16(af[u], bfr[v], acc[u][v], 0, 0, 0);
    }
    {
      bf16x8 af[4], bfr[4];
#pragma unroll
      for (int u = 0; u < 4; ++u) af[u] = *(bf16x8*)&Jb1[(jrow + u * 16) * 32 + kq];
#pragma unroll
      for (int v = 0; v < 4; ++v) bfr[v] = *(bf16x8*)&Ib1[(irow + v * 16) * 32 + kq];
#pragma unroll
      for (int u = 0; u < 4; ++u)
#pragma unroll
        for (int v = 0; v < 4; ++v)
          acc[u][v] = __builtin_amdgcn_mfma_f32_16x16x32_bf16(af[u], bfr[v], acc[u][v], 0, 0, 0);
    }
    __syncthreads();
  }

  // direct store G[i][j] (+ transpose-tile write for off-diag)
#pragma unroll
  for (int v = 0; v < 4; ++v) {
    int il = wc * 64 + v * 16 + c;
    int ig = by * 128 + il;
    float ri = rsq[ig];
    float rsv = 0.f;
#pragma unroll
    for (int u = 0; u < 4; ++u) {
      int jl0 = wr * 64 + u * 16 + quad * 4;
      int jb0i = bx * 128 + jl0;
      float4 rj = *(const float4*)(rsq + jb0i);
      const float* rjp = (const float*)&rj;
      f32x4 a = acc[u][v];
      f16x4 st;
      if (z == 0) {
#pragma unroll
        for (int reg = 0; reg < 4; ++reg) {
          float sq = fmaxf(ri + rjp[reg] - 2.0f * a[reg], 0.0f);
          float val = sqrtf(sq);
          st[reg] = (_Float16)val;
          rsv += val;
        }
      } else {
#pragma unroll
        for (int reg = 0; reg < 4; ++reg) {
          float sq = fmaxf(ri + rjp[reg] - 2.0f * a[reg], 0.0f);
          st[reg] = (_Float16)expf(-sq);
        }
      }
      *(f16x4*)(G + (size_t)ig * N + jb0i) = st;
      if (offdiag) {
#pragma unroll
        for (int reg = 0; reg < 4; ++reg) tp[(jl0 + reg) * 136 + il] = st[reg];
      }
    }
    if (z == 0) {
      rsv += __shfl_xor(rsv, 16, 64);
      rsv += __shfl_xor(rsv, 32, 64);
      if (lane < 16) atomicAdd(&rowsum[ig], rsv);
    }
  }

  // mirrored store G[j][i]: 16 lanes/row, 256 B contiguous -> full-line writes
  if (offdiag) {
    __syncthreads();
    int rloc = tid >> 4;
    int cseg = tid & 15;
#pragma unroll
    for (int it = 0; it < 8; ++it) {
      int jl = it * 16 + rloc;
      int jg = bx * 128 + jl;
      f16x8 v8 = *(f16x8*)&tp[jl * 136 + cseg * 8];
      *(f16x8*)(G + (size_t)jg * N + by * 128 + cseg * 8) = v8;
      if (z == 0) {
        float csum = 0.f;
#pragma unroll
        for (int e = 0; e < 8; ++e) csum += (float)v8[e];
        csum += __shfl_xor(csum, 1, 64);
        csum += __shfl_xor(csum, 2, 64);
        csum += __shfl_xor(csum, 4, 64);
        csum += __shfl_xor(csum, 8, 64);
        if (cseg == 0) atomicAdd(&rowsum[jg], csum);
      }
    }
  }
}

// ---------------- Row pass: branch-free bitonic top-10 + dense loss ----------------
__global__ __launch_bounds__(256) void k_rowpass(const f16* __restrict__ Gs,
                                                 const f16* __restrict__ Gw,
                                                 const int* __restrict__ ids,
                                                 const float* __restrict__ rowsum,
                                                 int* __restrict__ topk,
                                                 double* __restrict__ pd) {
  __shared__ u32 lds[256 * TOPK];  // 10 KB
  __shared__ double dred[4];
  int i = blockIdx.x, tid = threadIdx.x;
  int idi = ids[i];
  float invm = 1.0f / (rowsum[i] * INV_N);
  const u16* srow = (const u16*)(Gs + (size_t)i * N);
  const u16* wrow = (const u16*)(Gw + (size_t)i * N);
  u32 key[16];
  float dsum = 0.f;
  int j0 = tid * 16;
#pragma unroll
  for (int h = 0; h < 2; ++h) {
    int jb = j0 + h * 8;
    u16x8 sv = *(const u16x8*)(srow + jb);
    u16x8 wv = *(const u16x8*)(wrow + jb);
    int4 id0 = *(const int4*)(ids + jb);
    int4 id1 = *(const int4*)(ids + jb + 4);
    const int* idp = (const int*)&id0;
    const int* idp1 = (const int*)&id1;
#pragma unroll
    for (int e = 0; e < 8; ++e) {
      int j = jb + e;
      u16 hw = wv[e];
      float wp = f16tof(hw);
      if (j != i) {
        float sdn = f16tof(sv[e]) * invm;
        float r = fmaxf(1.0f - sdn, 0.0f); r *= r;
        dsum += r + 0.5f * wp * (sdn * sdn - r);
      }
      int idj = (e < 4) ? idp[e] : idp1[e - 4];
      u16 hk = (idj == idi) ? (u16)0x3C00 : hw;
      key[h * 8 + e] = ((u32)hk << 16) | (u32)(4095 - j);
    }
  }
  // bitonic sort-16 descending (branch-free, high ILP)
#pragma unroll
  for (int kk = 2; kk <= 16; kk <<= 1) {
#pragma unroll
    for (int jj = kk >> 1; jj > 0; jj >>= 1) {
#pragma unroll
      for (int ii = 0; ii < 16; ++ii) {
        int ll = ii ^ jj;
        if (ll > ii) {
          bool desc = ((ii & kk) == 0);
          u32 a = key[ii], b = key[ll];
          bool sw = desc ? (a < b) : (a > b);
          key[ii] = sw ? b : a;
          key[ll] = sw ? a : b;
        }
      }
    }
  }
  double dl = (double)dsum;
  for (int off = 32; off > 0; off >>= 1) dl += __shfl_down(dl, off, 64);
  if ((tid & 63) == 0) dred[tid >> 6] = dl;
#pragma unroll
  for (int o = 0; o < TOPK; ++o) lds[tid * TOPK + o] = key[o];
  __syncthreads();
  for (int off = 128; off >= 1; off >>= 1) {
    if (tid < off) {
      u32 out[TOPK];
      int pa = 0, pb = 0;
#pragma unroll
      for (int o = 0; o < TOPK; ++o) {
        u32 ka = lds[tid * TOPK + pa];
        u32 kb = lds[(tid + off) * TOPK + pb];
        bool ta = ka >= kb;
        out[o] = ta ? ka : kb;
        pa += ta ? 1 : 0;
        pb += ta ? 0 : 1;
      }
#pragma unroll
      for (int o = 0; o < TOPK; ++o) lds[tid * TOPK + o] = out[o];
    }
    __syncthreads();
  }
  if (tid == 0) {
#pragma unroll
    for (int o = 0; o < TOPK; ++o)
      topk[i * TOPK + o] = 4095 - (int)(lds[o] & 0xFFFu);
    pd[i] = dred[0] + dred[1] + dred[2] + dred[3];
  }
}

// ---------------- mutual-kNN lists (64 blocks x 64 thr for CU coverage) ----------------
__global__ __launch_bounds__(64) void k_buildV(const int* __restrict__ topk,
                                               int* __restrict__ L,
                                               int* __restrict__ cnt) {
  int i = blockIdx.x * 64 + threadIdx.x;
  if (i >= N) return;
  int c = 0;
  for (int r = 0; r < TOPK; ++r) {
    int j = topk[i * TOPK + r];
    bool mut = false;
    for (int q = 0; q < TOPK; ++q) mut |= (topk[j * TOPK + q] == i);
    if (mut) L[i * TOPK + c++] = j;
  }
  cnt[i] = c;
}

// ---------------- sparse W_C loss, one wave per task ----------------
__global__ __launch_bounds__(256) void k_wc(const int* __restrict__ topk,
                                            const int* __restrict__ L,
                                            const int* __restrict__ cnt,
                                            const bf16* __restrict__ S,
                                            const float* __restrict__ rsq,
                                            const float* __restrict__ rowsum,
                                            double* __restrict__ pw) {
  int tid = threadIdx.x;
  int lane = tid & 63;
  int wv = tid >> 6;
  int task = blockIdx.x * 4 + wv;
  int i = task / TOPK_HALF, m = task % TOPK_HALF;
  int r = topk[i * TOPK + m];
  int cr = cnt[r];
  double local = 0.0;
  if (cr > 0) {
    float denom = (float)(cr > 1 ? cr : 1);
    int lval = (lane < cr) ? L[r * TOPK + lane] : -1;
    int Lr[TOPK];
#pragma unroll
    for (int a = 0; a < TOPK; ++a) Lr[a] = __shfl(lval, a, 64);
    float invmi = 1.0f / (rowsum[i] * INV_N);
    float rsqi = rsq[i];
    bf16x8 vi = *(const bf16x8*)(S + (size_t)i * D + lane * 8);
    float fi[8];
#pragma unroll
    for (int k = 0; k < 8; ++k) fi[k] = (float)vi[k];
    int cj_l = 0; float mj_l = 1.0f;
    if (lane < cr) { cj_l = cnt[lval]; mj_l = rowsum[lval] * INV_N; }
    for (int jj = 0; jj < cr; ++jj) {
      int j = Lr[jj];
      if (j == i) continue;
      int cj = __shfl(cj_l, jj, 64);
      float mj = __shfl(mj_l, jj, 64);
      bf16x8 vj = *(const bf16x8*)(S + (size_t)j * D + lane * 8);
      float dot = 0.f;
#pragma unroll
      for (int k = 0; k < 8; ++k) dot = fmaf(fi[k], (float)vj[k], dot);
#pragma unroll
      for (int off = 32; off > 0; off >>= 1) dot += __shfl_xor(dot, off, 64);
      float sq = fmaxf(rsqi + rsq[j] - 2.0f * dot, 0.0f);
      float sr_ = sqrtf(sq);
      int ljb = (lane < cj) ? L[j * TOPK + lane] : -1;
      int match = 0;
#pragma unroll
      for (int a = 0; a < TOPK; ++a) match |= ((a < cr) && (ljb == Lr[a])) ? 1 : 0;
      int vv = __popcll(__ballot(match != 0));
      float wgt = (float)vv / denom;
      float sdij = sr_ * invmi;
      float sdji = sr_ / mj;
      float Rij = fmaxf(1.0f - sdij, 0.0f); Rij *= Rij;
      float Rji = fmaxf(1.0f - sdji, 0.0f); Rji *= Rji;
      float Fij = sdij * sdij - Rij;
      float Fji = sdji * sdji - Rji;
      local += (double)(wgt * (Fij + Fji));
    }
    local *= (1.0 / 20.0);
  }
  __shared__ double red[4];
  if (lane == 0) red[wv] = local;
  __syncthreads();
  if (tid == 0) pw[blockIdx.x] = red[0] + red[1] + red[2] + red[3];
}

// ---------------- final reduce ----------------
__global__ __launch_bounds__(256) void k_final(const double* __restrict__ pd,
                                               const double* __restrict__ pw,
                                               float* __restrict__ out) {
  int tid = threadIdx.x;
  double s = 0.0;
  for (int i = tid; i < N; i += 256) s += pd[i];
  for (int i = tid; i < WC_BLOCKS; i += 256) s += pw[i];
  for (int off = 32; off > 0; off >>= 1) s += __shfl_down(s, off, 64);
  __shared__ double red[4];
  if ((tid & 63) == 0) red[tid >> 6] = s;
  __syncthreads();
  if (tid == 0)
    out[0] = (float)((red[0] + red[1] + red[2] + red[3]) /
                     ((double)N * (double)(N - 1)));
}

extern "C" void kernel_launch(void* const* d_in, const int* in_sizes, int n_in,
                              void* d_out, int out_size, void* d_ws, size_t ws_size,
                              hipStream_t stream) {
  const float* s_emb = (const float*)d_in[0];
  const float* t_emb = (const float*)d_in[1];
  const int* ids = (const int*)d_in[2];
  float* out = (float*)d_out;

  char* ws = (char*)d_ws;
  size_t off = 0;
  bf16* snorm = (bf16*)(ws + off); off += (size_t)N * D * 2;        // 4 MB
  bf16* tnorm = (bf16*)(ws + off); off += (size_t)N * D * 2;        // 4 MB
  f16*  Gsd   = (f16*)(ws + off);  off += (size_t)N * N * 2;        // 32 MB
  f16*  Gwp   = (f16*)(ws + off);  off += (size_t)N * N * 2;        // 32 MB
  float* rsq_s = (float*)(ws + off); off += (size_t)N * 4;
  float* rsq_t = (float*)(ws + off); off += (size_t)N * 4;
  float* rowsum= (float*)(ws + off); off += (size_t)N * 4;
  int*   topk  = (int*)(ws + off);   off += (size_t)N * TOPK * 4;
  int*   L     = (int*)(ws + off);   off += (size_t)N * TOPK * 4;
  int*   cnt   = (int*)(ws + off);   off += (size_t)N * 4;
  off = (off + 15) & ~(size_t)15;
  double* pd   = (double*)(ws + off); off += (size_t)N * 8;
  double* pw   = (double*)(ws + off); off += (size_t)WC_BLOCKS * 8;

  k_normalize2<<<2 * N, 256, 0, stream>>>(s_emb, t_emb, snorm, tnorm,
                                          rsq_s, rsq_t, rowsum);
  k_dgram3<<<dim3(TRI_BLOCKS, 2), 256, 0, stream>>>(snorm, tnorm, rsq_s, rsq_t,
                                                    Gsd, Gwp, rowsum);
  k_rowpass<<<N, 256, 0, stream>>>(Gsd, Gwp, ids, rowsum, topk, pd);
  k_buildV<<<N / 64, 64, 0, stream>>>(topk, L, cnt);
  k_wc<<<WC_BLOCKS, 256, 0, stream>>>(topk, L, cnt, snorm, rsq_s, rowsum, pw);
  k_final<<<1, 256, 0, stream>>>(pd, pw, out);
}

// Round 13
// 165.339 us; speedup vs baseline: 1.2819x; 1.1855x over previous
//
#include <hip/hip_runtime.h>
#include <math.h>

#define N 4096
#define D 512
#define TOPK 10
#define TOPK_HALF 5
#define NT 32
#define TRI_BLOCKS (NT * (NT + 1) / 2)   // 528
#define WC_BLOCKS (N * TOPK_HALF / 16)   // 1280: one 16-lane group per task
#define INV_N (1.0f / 4096.0f)

typedef __bf16 bf16;
typedef __bf16 bf16x8 __attribute__((ext_vector_type(8)));
typedef float f32x4 __attribute__((ext_vector_type(4)));
typedef _Float16 f16;
typedef _Float16 f16x4 __attribute__((ext_vector_type(4)));
typedef _Float16 f16x8 __attribute__((ext_vector_type(8)));
typedef unsigned short u16;
typedef unsigned short u16x8 __attribute__((ext_vector_type(8)));
typedef unsigned int u32;

__device__ __forceinline__ void gl_lds16(const void* g, void* l) {
  __builtin_amdgcn_global_load_lds(
      (const __attribute__((address_space(1))) void*)g,
      (__attribute__((address_space(3))) void*)l, 16, 0, 0);
}

__device__ __forceinline__ float f16tof(u16 h) {
  return (float)__builtin_bit_cast(_Float16, h);
}

// ---------------- K0: L2-normalize both matrices ----------------
__global__ __launch_bounds__(256) void k_normalize2(const float* __restrict__ xs,
                                                    const float* __restrict__ xt,
                                                    bf16* __restrict__ ys,
                                                    bf16* __restrict__ yt,
                                                    float* __restrict__ rsq_s,
                                                    float* __restrict__ rsq_t,
                                                    float* __restrict__ rowsum) {
  int b = blockIdx.x;
  int row = b & (N - 1);
  int is_t = b >> 12;
  const float* x = is_t ? xt : xs;
  bf16* y = is_t ? yt : ys;
  float* rowsq = is_t ? rsq_t : rsq_s;
  int tid = threadIdx.x;
  const float* xr = x + (size_t)row * D;
  float v0 = xr[tid], v1 = xr[tid + 256];
  float ss = v0 * v0 + v1 * v1;
  __shared__ float red[4];
  for (int off = 32; off > 0; off >>= 1) ss += __shfl_down(ss, off, 64);
  if ((tid & 63) == 0) red[tid >> 6] = ss;
  __syncthreads();
  float tot = red[0] + red[1] + red[2] + red[3];
  float inv = 1.0f / fmaxf(sqrtf(tot), 1e-12f);
  bf16 b0 = (bf16)(v0 * inv), b1 = (bf16)(v1 * inv);
  bf16* yr = y + (size_t)row * D;
  yr[tid] = b0; yr[tid + 256] = b1;
  float f0 = (float)b0, f1 = (float)b1;
  float s2 = f0 * f0 + f1 * f1;
  for (int off = 32; off > 0; off >>= 1) s2 += __shfl_down(s2, off, 64);
  __syncthreads();
  if ((tid & 63) == 0) red[tid >> 6] = s2;
  __syncthreads();
  if (tid == 0) {
    rowsq[row] = red[0] + red[1] + red[2] + red[3];
    if (!is_t) rowsum[row] = 0.f;
  }
}

// ---------------- Gram: triangular BK=64 K-loop + coalesced mirrored epilogue ----------------
__global__ __launch_bounds__(256) void k_dgram3(const bf16* __restrict__ S,
                                                const bf16* __restrict__ T,
                                                const float* __restrict__ rsq_s,
                                                const float* __restrict__ rsq_t,
                                                f16* __restrict__ Gsd,
                                                f16* __restrict__ Gwp,
                                                float* __restrict__ rowsum) {
  __shared__ __align__(16) char sm[128 * 136 * 2];   // 34816 B: staging / transpose union
  bf16* Jb0 = (bf16*)sm;
  bf16* Jb1 = (bf16*)(sm + 8192);
  bf16* Ib0 = (bf16*)(sm + 16384);
  bf16* Ib1 = (bf16*)(sm + 24576);
  f16* tp = (f16*)sm;                                // [128][136] padded transpose tile

  int z = blockIdx.y;
  const bf16* Y = z ? T : S;
  const float* rsq = z ? rsq_t : rsq_s;
  f16* G = z ? Gwp : Gsd;

  int t = blockIdx.x, by = 0;
  while (t >= NT - by) { t -= NT - by; ++by; }
  int bx = by + t;
  bool offdiag = (bx != by);

  int tid = threadIdx.x;
  int lane = tid & 63, w = tid >> 6;
  int wr = w >> 1, wc = w & 1;
  int quad = lane >> 4, c = lane & 15;

  const char* Jbase = (const char*)(Y + (size_t)(bx * 128) * D);
  const char* Ibase = (const char*)(Y + (size_t)(by * 128) * D);
  int r0 = tid >> 2, q0 = tid & 3;
  int r1 = (tid + 256) >> 2, q1 = (tid + 256) & 3;
  size_t so0 = (size_t)r0 * (D * 2) + q0 * 16;
  size_t so1 = (size_t)r1 * (D * 2) + q1 * 16;
  bf16* lJ0a = Jb0 + (size_t)w * 512;  bf16* lJ0b = Jb0 + (size_t)(256 + w * 64) * 8;
  bf16* lJ1a = Jb1 + (size_t)w * 512;  bf16* lJ1b = Jb1 + (size_t)(256 + w * 64) * 8;
  bf16* lI0a = Ib0 + (size_t)w * 512;  bf16* lI0b = Ib0 + (size_t)(256 + w * 64) * 8;
  bf16* lI1a = Ib1 + (size_t)w * 512;  bf16* lI1b = Ib1 + (size_t)(256 + w * 64) * 8;

  int jrow = wr * 64 + c;
  int irow = wc * 64 + c;
  int kq = quad * 8;

  f32x4 acc[4][4] = {};
  for (int k0 = 0; k0 < D; k0 += 64) {
    size_t kb = (size_t)k0 * 2;
    gl_lds16(Jbase + so0 + kb,      lJ0a);
    gl_lds16(Jbase + so1 + kb,      lJ0b);
    gl_lds16(Jbase + so0 + kb + 64, lJ1a);
    gl_lds16(Jbase + so1 + kb + 64, lJ1b);
    gl_lds16(Ibase + so0 + kb,      lI0a);
    gl_lds16(Ibase + so1 + kb,      lI0b);
    gl_lds16(Ibase + so0 + kb + 64, lI1a);
    gl_lds16(Ibase + so1 + kb + 64, lI1b);
    __syncthreads();
    {
      bf16x8 af[4], bfr[4];
#pragma unroll
      for (int u = 0; u < 4; ++u) af[u] = *(bf16x8*)&Jb0[(jrow + u * 16) * 32 + kq];
#pragma unroll
      for (int v = 0; v < 4; ++v) bfr[v] = *(bf16x8*)&Ib0[(irow + v * 16) * 32 + kq];
#pragma unroll
      for (int u = 0; u < 4; ++u)
#pragma unroll
        for (int v = 0; v < 4; ++v)
          acc[u][v] = __builtin_amdgcn_mfma_f32_16x16x32_bf16(af[u], bfr[v], acc[u][v], 0, 0, 0);
    }
    {
      bf16x8 af[4], bfr[4];
#pragma unroll
      for (int u = 0; u < 4; ++u) af[u] = *(bf16x8*)&Jb1[(jrow + u * 16) * 32 + kq];
#pragma unroll
      for (int v = 0; v < 4; ++v) bfr[v] = *(bf16x8*)&Ib1[(irow + v * 16) * 32 + kq];
#pragma unroll
      for (int u = 0; u < 4; ++u)
#pragma unroll
        for (int v = 0; v < 4; ++v)
          acc[u][v] = __builtin_amdgcn_mfma_f32_16x16x32_bf16(af[u], bfr[v], acc[u][v], 0, 0, 0);
    }
    __syncthreads();
  }

  // direct store G[i][j] (+ transpose-tile write for off-diag)
#pragma unroll
  for (int v = 0; v < 4; ++v) {
    int il = wc * 64 + v * 16 + c;
    int ig = by * 128 + il;
    float ri = rsq[ig];
    float rsv = 0.f;
#pragma unroll
    for (int u = 0; u < 4; ++u) {
      int jl0 = wr * 64 + u * 16 + quad * 4;
      int jb0i = bx * 128 + jl0;
      float4 rj = *(const float4*)(rsq + jb0i);
      const float* rjp = (const float*)&rj;
      f32x4 a = acc[u][v];
      f16x4 st;
      if (z == 0) {
#pragma unroll
        for (int reg = 0; reg < 4; ++reg) {
          float sq = fmaxf(ri + rjp[reg] - 2.0f * a[reg], 0.0f);
          float val = sqrtf(sq);
          st[reg] = (_Float16)val;
          rsv += val;
        }
      } else {
#pragma unroll
        for (int reg = 0; reg < 4; ++reg) {
          float sq = fmaxf(ri + rjp[reg] - 2.0f * a[reg], 0.0f);
          st[reg] = (_Float16)expf(-sq);
        }
      }
      *(f16x4*)(G + (size_t)ig * N + jb0i) = st;
      if (offdiag) {
#pragma unroll
        for (int reg = 0; reg < 4; ++reg) tp[(jl0 + reg) * 136 + il] = st[reg];
      }
    }
    if (z == 0) {
      rsv += __shfl_xor(rsv, 16, 64);
      rsv += __shfl_xor(rsv, 32, 64);
      if (lane < 16) atomicAdd(&rowsum[ig], rsv);
    }
  }

  // mirrored store G[j][i]: 16 lanes/row, 256 B contiguous -> full-line writes
  if (offdiag) {
    __syncthreads();
    int rloc = tid >> 4;
    int cseg = tid & 15;
#pragma unroll
    for (int it = 0; it < 8; ++it) {
      int jl = it * 16 + rloc;
      int jg = bx * 128 + jl;
      f16x8 v8 = *(f16x8*)&tp[jl * 136 + cseg * 8];
      *(f16x8*)(G + (size_t)jg * N + by * 128 + cseg * 8) = v8;
      if (z == 0) {
        float csum = 0.f;
#pragma unroll
        for (int e = 0; e < 8; ++e) csum += (float)v8[e];
        csum += __shfl_xor(csum, 1, 64);
        csum += __shfl_xor(csum, 2, 64);
        csum += __shfl_xor(csum, 4, 64);
        csum += __shfl_xor(csum, 8, 64);
        if (cseg == 0) atomicAdd(&rowsum[jg], csum);
      }
    }
  }
}

// ---------------- Row pass: branch-free bitonic top-10 + dense loss ----------------
__global__ __launch_bounds__(256) void k_rowpass(const f16* __restrict__ Gs,
                                                 const f16* __restrict__ Gw,
                                                 const int* __restrict__ ids,
                                                 const float* __restrict__ rowsum,
                                                 int* __restrict__ topk,
                                                 double* __restrict__ pd) {
  __shared__ u32 lds[256 * TOPK];  // 10 KB
  __shared__ double dred[4];
  int i = blockIdx.x, tid = threadIdx.x;
  int idi = ids[i];
  float invm = 1.0f / (rowsum[i] * INV_N);
  const u16* srow = (const u16*)(Gs + (size_t)i * N);
  const u16* wrow = (const u16*)(Gw + (size_t)i * N);
  u32 key[16];
  float dsum = 0.f;
  int j0 = tid * 16;
#pragma unroll
  for (int h = 0; h < 2; ++h) {
    int jb = j0 + h * 8;
    u16x8 sv = *(const u16x8*)(srow + jb);
    u16x8 wv = *(const u16x8*)(wrow + jb);
    int4 id0 = *(const int4*)(ids + jb);
    int4 id1 = *(const int4*)(ids + jb + 4);
    const int* idp = (const int*)&id0;
    const int* idp1 = (const int*)&id1;
#pragma unroll
    for (int e = 0; e < 8; ++e) {
      int j = jb + e;
      u16 hw = wv[e];
      float wp = f16tof(hw);
      if (j != i) {
        float sdn = f16tof(sv[e]) * invm;
        float r = fmaxf(1.0f - sdn, 0.0f); r *= r;
        dsum += r + 0.5f * wp * (sdn * sdn - r);
      }
      int idj = (e < 4) ? idp[e] : idp1[e - 4];
      u16 hk = (idj == idi) ? (u16)0x3C00 : hw;
      key[h * 8 + e] = ((u32)hk << 16) | (u32)(4095 - j);
    }
  }
  // bitonic sort-16 descending (branch-free, high ILP)
#pragma unroll
  for (int kk = 2; kk <= 16; kk <<= 1) {
#pragma unroll
    for (int jj = kk >> 1; jj > 0; jj >>= 1) {
#pragma unroll
      for (int ii = 0; ii < 16; ++ii) {
        int ll = ii ^ jj;
        if (ll > ii) {
          bool desc = ((ii & kk) == 0);
          u32 a = key[ii], b = key[ll];
          bool sw = desc ? (a < b) : (a > b);
          key[ii] = sw ? b : a;
          key[ll] = sw ? a : b;
        }
      }
    }
  }
  double dl = (double)dsum;
  for (int off = 32; off > 0; off >>= 1) dl += __shfl_down(dl, off, 64);
  if ((tid & 63) == 0) dred[tid >> 6] = dl;
#pragma unroll
  for (int o = 0; o < TOPK; ++o) lds[tid * TOPK + o] = key[o];
  __syncthreads();
  for (int off = 128; off >= 1; off >>= 1) {
    if (tid < off) {
      u32 out[TOPK];
      int pa = 0, pb = 0;
#pragma unroll
      for (int o = 0; o < TOPK; ++o) {
        u32 ka = lds[tid * TOPK + pa];
        u32 kb = lds[(tid + off) * TOPK + pb];
        bool ta = ka >= kb;
        out[o] = ta ? ka : kb;
        pa += ta ? 1 : 0;
        pb += ta ? 0 : 1;
      }
#pragma unroll
      for (int o = 0; o < TOPK; ++o) lds[tid * TOPK + o] = out[o];
    }
    __syncthreads();
  }
  if (tid == 0) {
#pragma unroll
    for (int o = 0; o < TOPK; ++o)
      topk[i * TOPK + o] = 4095 - (int)(lds[o] & 0xFFFu);
    pd[i] = dred[0] + dred[1] + dred[2] + dred[3];
  }
}

// ---------------- mutual-kNN lists (64 blocks x 64 thr for CU coverage) ----------------
__global__ __launch_bounds__(64) void k_buildV(const int* __restrict__ topk,
                                               int* __restrict__ L,
                                               int* __restrict__ cnt) {
  int i = blockIdx.x * 64 + threadIdx.x;
  if (i >= N) return;
  int c = 0;
  for (int r = 0; r < TOPK; ++r) {
    int j = topk[i * TOPK + r];
    bool mut = false;
    for (int q = 0; q < TOPK; ++q) mut |= (topk[j * TOPK + q] == i);
    if (mut) L[i * TOPK + c++] = j;
  }
  cnt[i] = c;
}

// ---------------- sparse W_C loss: one 16-lane group per task, sd from Gsd ----------------
// Lane gl handles neighbor j = L_r[gl] end-to-end: 10 pipelined L_j loads,
// 100 branch-free compares for vv, one f16 sd load. One latency round per task.
__global__ __launch_bounds__(256) void k_wc(const int* __restrict__ topk,
                                            const int* __restrict__ L,
                                            const int* __restrict__ cnt,
                                            const f16* __restrict__ Gsd,
                                            const float* __restrict__ rowsum,
                                            double* __restrict__ pw) {
  __shared__ double red[16];
  int tid = threadIdx.x;
  int grp = tid >> 4;          // 0..15 group within block
  int gl = tid & 15;           // lane within group
  int task = blockIdx.x * 16 + grp;   // < N*TOPK_HALF
  int i = task / TOPK_HALF, m = task % TOPK_HALF;
  int r = topk[i * TOPK + m];
  int cr = cnt[r];
  float invmi = 1.0f / (rowsum[i] * INV_N);
  int lval = (gl < cr) ? L[r * TOPK + gl] : -1;
  int Lr[TOPK];
#pragma unroll
  for (int a = 0; a < TOPK; ++a) Lr[a] = __shfl(lval, a, 16);
  float contrib = 0.f;
  if (gl < cr) {
    int j = lval;
    if (j != i) {
      int cj = cnt[j];
      float mj = rowsum[j] * INV_N;
      float sr_ = f16tof(((const u16*)Gsd)[(size_t)i * N + j]);
      int lj[TOPK];
#pragma unroll
      for (int b = 0; b < TOPK; ++b) lj[b] = L[j * TOPK + b];  // independent, pipelined
      int vv = 0;
#pragma unroll
      for (int b = 0; b < TOPK; ++b) {
        if (b < cj) {
#pragma unroll
          for (int a = 0; a < TOPK; ++a)
            vv += ((a < cr) && (lj[b] == Lr[a])) ? 1 : 0;
        }
      }
      float denom = (float)(cr > 1 ? cr : 1);
      float wgt = (float)vv / denom;
      float sdij = sr_ * invmi;
      float sdji = sr_ / mj;
      float Rij = fmaxf(1.0f - sdij, 0.0f); Rij *= Rij;
      float Rji = fmaxf(1.0f - sdji, 0.0f); Rji *= Rji;
      float Fij = sdij * sdij - Rij;
      float Fji = sdji * sdji - Rji;
      contrib = wgt * (Fij + Fji);
    }
  }
  double local = (double)contrib;
  local += __shfl_xor(local, 1, 16);
  local += __shfl_xor(local, 2, 16);
  local += __shfl_xor(local, 4, 16);
  local += __shfl_xor(local, 8, 16);
  if (gl == 0) red[grp] = local;
  __syncthreads();
  if (tid == 0) {
    double s = 0.0;
#pragma unroll
    for (int g = 0; g < 16; ++g) s += red[g];
    pw[blockIdx.x] = s * (1.0 / 20.0);
  }
}

// ---------------- final reduce ----------------
__global__ __launch_bounds__(256) void k_final(const double* __restrict__ pd,
                                               const double* __restrict__ pw,
                                               float* __restrict__ out) {
  int tid = threadIdx.x;
  double s = 0.0;
  for (int i = tid; i < N; i += 256) s += pd[i];
  for (int i = tid; i < WC_BLOCKS; i += 256) s += pw[i];
  for (int off = 32; off > 0; off >>= 1) s += __shfl_down(s, off, 64);
  __shared__ double red[4];
  if ((tid & 63) == 0) red[tid >> 6] = s;
  __syncthreads();
  if (tid == 0)
    out[0] = (float)((red[0] + red[1] + red[2] + red[3]) /
                     ((double)N * (double)(N - 1)));
}

extern "C" void kernel_launch(void* const* d_in, const int* in_sizes, int n_in,
                              void* d_out, int out_size, void* d_ws, size_t ws_size,
                              hipStream_t stream) {
  const float* s_emb = (const float*)d_in[0];
  const float* t_emb = (const float*)d_in[1];
  const int* ids = (const int*)d_in[2];
  float* out = (float*)d_out;

  char* ws = (char*)d_ws;
  size_t off = 0;
  bf16* snorm = (bf16*)(ws + off); off += (size_t)N * D * 2;        // 4 MB
  bf16* tnorm = (bf16*)(ws + off); off += (size_t)N * D * 2;        // 4 MB
  f16*  Gsd   = (f16*)(ws + off);  off += (size_t)N * N * 2;        // 32 MB
  f16*  Gwp   = (f16*)(ws + off);  off += (size_t)N * N * 2;        // 32 MB
  float* rsq_s = (float*)(ws + off); off += (size_t)N * 4;
  float* rsq_t = (float*)(ws + off); off += (size_t)N * 4;
  float* rowsum= (float*)(ws + off); off += (size_t)N * 4;
  int*   topk  = (int*)(ws + off);   off += (size_t)N * TOPK * 4;
  int*   L     = (int*)(ws + off);   off += (size_t)N * TOPK * 4;
  int*   cnt   = (int*)(ws + off);   off += (size_t)N * 4;
  off = (off + 15) & ~(size_t)15;
  double* pd   = (double*)(ws + off); off += (size_t)N * 8;
  double* pw   = (double*)(ws + off); off += (size_t)WC_BLOCKS * 8;

  k_normalize2<<<2 * N, 256, 0, stream>>>(s_emb, t_emb, snorm, tnorm,
                                          rsq_s, rsq_t, rowsum);
  k_dgram3<<<dim3(TRI_BLOCKS, 2), 256, 0, stream>>>(snorm, tnorm, rsq_s, rsq_t,
                                                    Gsd, Gwp, rowsum);
  k_rowpass<<<N, 256, 0, stream>>>(Gsd, Gwp, ids, rowsum, topk, pd);
  k_buildV<<<N / 64, 64, 0, stream>>>(topk, L, cnt);
  k_wc<<<WC_BLOCKS, 256, 0, stream>>>(topk, L, cnt, Gsd, rowsum, pw);
  k_final<<<1, 256, 0, stream>>>(pd, pw, out);
}

// Round 14
// 164.528 us; speedup vs baseline: 1.2882x; 1.0049x over previous
//
#include <hip/hip_runtime.h>
#include <math.h>

#define N 4096
#define D 512
#define TOPK 10
#define TOPK_HALF 5
#define NT 32
#define TRI_BLOCKS (NT * (NT + 1) / 2)   // 528
#define WC_BLOCKS (N * TOPK_HALF / 16)   // 1280: one 16-lane group per task
#define INV_N (1.0f / 4096.0f)
#define TPAD 132                          // transpose-tile pad: 2*TPAD%32==8 -> conflict-free

typedef __bf16 bf16;
typedef __bf16 bf16x8 __attribute__((ext_vector_type(8)));
typedef float f32x4 __attribute__((ext_vector_type(4)));
typedef _Float16 f16;
typedef _Float16 f16x4 __attribute__((ext_vector_type(4)));
typedef _Float16 f16x8 __attribute__((ext_vector_type(8)));
typedef unsigned short u16;
typedef unsigned short u16x8 __attribute__((ext_vector_type(8)));
typedef unsigned int u32;

__device__ __forceinline__ void gl_lds16(const void* g, void* l) {
  __builtin_amdgcn_global_load_lds(
      (const __attribute__((address_space(1))) void*)g,
      (__attribute__((address_space(3))) void*)l, 16, 0, 0);
}

__device__ __forceinline__ float f16tof(u16 h) {
  return (float)__builtin_bit_cast(_Float16, h);
}

// ---------------- K0: L2-normalize both matrices ----------------
__global__ __launch_bounds__(256) void k_normalize2(const float* __restrict__ xs,
                                                    const float* __restrict__ xt,
                                                    bf16* __restrict__ ys,
                                                    bf16* __restrict__ yt,
                                                    float* __restrict__ rsq_s,
                                                    float* __restrict__ rsq_t,
                                                    float* __restrict__ rowsum) {
  int b = blockIdx.x;
  int row = b & (N - 1);
  int is_t = b >> 12;
  const float* x = is_t ? xt : xs;
  bf16* y = is_t ? yt : ys;
  float* rowsq = is_t ? rsq_t : rsq_s;
  int tid = threadIdx.x;
  const float* xr = x + (size_t)row * D;
  float v0 = xr[tid], v1 = xr[tid + 256];
  float ss = v0 * v0 + v1 * v1;
  __shared__ float red[4];
  for (int off = 32; off > 0; off >>= 1) ss += __shfl_down(ss, off, 64);
  if ((tid & 63) == 0) red[tid >> 6] = ss;
  __syncthreads();
  float tot = red[0] + red[1] + red[2] + red[3];
  float inv = 1.0f / fmaxf(sqrtf(tot), 1e-12f);
  bf16 b0 = (bf16)(v0 * inv), b1 = (bf16)(v1 * inv);
  bf16* yr = y + (size_t)row * D;
  yr[tid] = b0; yr[tid + 256] = b1;
  float f0 = (float)b0, f1 = (float)b1;
  float s2 = f0 * f0 + f1 * f1;
  for (int off = 32; off > 0; off >>= 1) s2 += __shfl_down(s2, off, 64);
  __syncthreads();
  if ((tid & 63) == 0) red[tid >> 6] = s2;
  __syncthreads();
  if (tid == 0) {
    rowsq[row] = red[0] + red[1] + red[2] + red[3];
    if (!is_t) rowsum[row] = 0.f;
  }
}

// ---------------- Gram: triangular BK=64 K-loop + coalesced mirrored epilogue ----------------
__global__ __launch_bounds__(256) void k_dgram3(const bf16* __restrict__ S,
                                                const bf16* __restrict__ T,
                                                const float* __restrict__ rsq_s,
                                                const float* __restrict__ rsq_t,
                                                f16* __restrict__ Gsd,
                                                f16* __restrict__ Gwp,
                                                float* __restrict__ rowsum) {
  __shared__ __align__(16) char sm[128 * TPAD * 2];  // 33792 B: staging (32K) / transpose union
  bf16* Jb0 = (bf16*)sm;
  bf16* Jb1 = (bf16*)(sm + 8192);
  bf16* Ib0 = (bf16*)(sm + 16384);
  bf16* Ib1 = (bf16*)(sm + 24576);
  f16* tp = (f16*)sm;                                // [128][TPAD] padded transpose tile

  int z = blockIdx.y;
  const bf16* Y = z ? T : S;
  const float* rsq = z ? rsq_t : rsq_s;
  f16* G = z ? Gwp : Gsd;

  int t = blockIdx.x, by = 0;
  while (t >= NT - by) { t -= NT - by; ++by; }
  int bx = by + t;
  bool offdiag = (bx != by);

  int tid = threadIdx.x;
  int lane = tid & 63, w = tid >> 6;
  int wr = w >> 1, wc = w & 1;
  int quad = lane >> 4, c = lane & 15;

  const char* Jbase = (const char*)(Y + (size_t)(bx * 128) * D);
  const char* Ibase = (const char*)(Y + (size_t)(by * 128) * D);
  int r0 = tid >> 2, q0 = tid & 3;
  int r1 = (tid + 256) >> 2, q1 = (tid + 256) & 3;
  size_t so0 = (size_t)r0 * (D * 2) + q0 * 16;
  size_t so1 = (size_t)r1 * (D * 2) + q1 * 16;
  bf16* lJ0a = Jb0 + (size_t)w * 512;  bf16* lJ0b = Jb0 + (size_t)(256 + w * 64) * 8;
  bf16* lJ1a = Jb1 + (size_t)w * 512;  bf16* lJ1b = Jb1 + (size_t)(256 + w * 64) * 8;
  bf16* lI0a = Ib0 + (size_t)w * 512;  bf16* lI0b = Ib0 + (size_t)(256 + w * 64) * 8;
  bf16* lI1a = Ib1 + (size_t)w * 512;  bf16* lI1b = Ib1 + (size_t)(256 + w * 64) * 8;

  int jrow = wr * 64 + c;
  int irow = wc * 64 + c;
  int kq = quad * 8;

  f32x4 acc[4][4] = {};
  for (int k0 = 0; k0 < D; k0 += 64) {
    size_t kb = (size_t)k0 * 2;
    gl_lds16(Jbase + so0 + kb,      lJ0a);
    gl_lds16(Jbase + so1 + kb,      lJ0b);
    gl_lds16(Jbase + so0 + kb + 64, lJ1a);
    gl_lds16(Jbase + so1 + kb + 64, lJ1b);
    gl_lds16(Ibase + so0 + kb,      lI0a);
    gl_lds16(Ibase + so1 + kb,      lI0b);
    gl_lds16(Ibase + so0 + kb + 64, lI1a);
    gl_lds16(Ibase + so1 + kb + 64, lI1b);
    __syncthreads();
    {
      bf16x8 af[4], bfr[4];
#pragma unroll
      for (int u = 0; u < 4; ++u) af[u] = *(bf16x8*)&Jb0[(jrow + u * 16) * 32 + kq];
#pragma unroll
      for (int v = 0; v < 4; ++v) bfr[v] = *(bf16x8*)&Ib0[(irow + v * 16) * 32 + kq];
#pragma unroll
      for (int u = 0; u < 4; ++u)
#pragma unroll
        for (int v = 0; v < 4; ++v)
          acc[u][v] = __builtin_amdgcn_mfma_f32_16x16x32_bf16(af[u], bfr[v], acc[u][v], 0, 0, 0);
    }
    {
      bf16x8 af[4], bfr[4];
#pragma unroll
      for (int u = 0; u < 4; ++u) af[u] = *(bf16x8*)&Jb1[(jrow + u * 16) * 32 + kq];
#pragma unroll
      for (int v = 0; v < 4; ++v) bfr[v] = *(bf16x8*)&Ib1[(irow + v * 16) * 32 + kq];
#pragma unroll
      for (int u = 0; u < 4; ++u)
#pragma unroll
        for (int v = 0; v < 4; ++v)
          acc[u][v] = __builtin_amdgcn_mfma_f32_16x16x32_bf16(af[u], bfr[v], acc[u][v], 0, 0, 0);
    }
    __syncthreads();
  }

  // direct store G[i][j] (+ transpose-tile write for off-diag)
#pragma unroll
  for (int v = 0; v < 4; ++v) {
    int il = wc * 64 + v * 16 + c;
    int ig = by * 128 + il;
    float ri = rsq[ig];
    float rsv = 0.f;
#pragma unroll
    for (int u = 0; u < 4; ++u) {
      int jl0 = wr * 64 + u * 16 + quad * 4;
      int jb0i = bx * 128 + jl0;
      float4 rj = *(const float4*)(rsq + jb0i);
      const float* rjp = (const float*)&rj;
      f32x4 a = acc[u][v];
      f16x4 st;
      if (z == 0) {
#pragma unroll
        for (int reg = 0; reg < 4; ++reg) {
          float sq = fmaxf(ri + rjp[reg] - 2.0f * a[reg], 0.0f);
          float val = sqrtf(sq);
          st[reg] = (_Float16)val;
          rsv += val;
        }
      } else {
#pragma unroll
        for (int reg = 0; reg < 4; ++reg) {
          float sq = fmaxf(ri + rjp[reg] - 2.0f * a[reg], 0.0f);
          st[reg] = (_Float16)expf(-sq);
        }
      }
      *(f16x4*)(G + (size_t)ig * N + jb0i) = st;
      if (offdiag) {
#pragma unroll
        for (int reg = 0; reg < 4; ++reg) tp[(jl0 + reg) * TPAD + il] = st[reg];
      }
    }
    if (z == 0) {
      rsv += __shfl_xor(rsv, 16, 64);
      rsv += __shfl_xor(rsv, 32, 64);
      if (lane < 16) atomicAdd(&rowsum[ig], rsv);
    }
  }

  // mirrored store G[j][i]: 16 lanes/row, 256 B contiguous -> full-line writes
  if (offdiag) {
    __syncthreads();
    int rloc = tid >> 4;
    int cseg = tid & 15;
#pragma unroll
    for (int it = 0; it < 8; ++it) {
      int jl = it * 16 + rloc;
      int jg = bx * 128 + jl;
      f16x8 v8 = *(f16x8*)&tp[jl * TPAD + cseg * 8];
      *(f16x8*)(G + (size_t)jg * N + by * 128 + cseg * 8) = v8;
      if (z == 0) {
        float csum = 0.f;
#pragma unroll
        for (int e = 0; e < 8; ++e) csum += (float)v8[e];
        csum += __shfl_xor(csum, 1, 64);
        csum += __shfl_xor(csum, 2, 64);
        csum += __shfl_xor(csum, 4, 64);
        csum += __shfl_xor(csum, 8, 64);
        if (cseg == 0) atomicAdd(&rowsum[jg], csum);
      }
    }
  }
}

// ---------------- Row pass: bitonic top-10 + dense loss; register merge-path tree ----------------
__global__ __launch_bounds__(256) void k_rowpass(const f16* __restrict__ Gs,
                                                 const f16* __restrict__ Gw,
                                                 const int* __restrict__ ids,
                                                 const float* __restrict__ rowsum,
                                                 int* __restrict__ topk,
                                                 double* __restrict__ pd) {
  __shared__ u32 lds[256 * TOPK];  // 10 KB
  __shared__ double dred[4];
  int i = blockIdx.x, tid = threadIdx.x;
  int idi = ids[i];
  float invm = 1.0f / (rowsum[i] * INV_N);
  const u16* srow = (const u16*)(Gs + (size_t)i * N);
  const u16* wrow = (const u16*)(Gw + (size_t)i * N);
  u32 key[16];
  float dsum = 0.f;
  int j0 = tid * 16;
#pragma unroll
  for (int h = 0; h < 2; ++h) {
    int jb = j0 + h * 8;
    u16x8 sv = *(const u16x8*)(srow + jb);
    u16x8 wv = *(const u16x8*)(wrow + jb);
    int4 id0 = *(const int4*)(ids + jb);
    int4 id1 = *(const int4*)(ids + jb + 4);
    const int* idp = (const int*)&id0;
    const int* idp1 = (const int*)&id1;
#pragma unroll
    for (int e = 0; e < 8; ++e) {
      int j = jb + e;
      u16 hw = wv[e];
      float wp = f16tof(hw);
      if (j != i) {
        float sdn = f16tof(sv[e]) * invm;
        float r = fmaxf(1.0f - sdn, 0.0f); r *= r;
        dsum += r + 0.5f * wp * (sdn * sdn - r);
      }
      int idj = (e < 4) ? idp[e] : idp1[e - 4];
      u16 hk = (idj == idi) ? (u16)0x3C00 : hw;
      key[h * 8 + e] = ((u32)hk << 16) | (u32)(4095 - j);
    }
  }
  // bitonic sort-16 descending (branch-free)
#pragma unroll
  for (int kk = 2; kk <= 16; kk <<= 1) {
#pragma unroll
    for (int jj = kk >> 1; jj > 0; jj >>= 1) {
#pragma unroll
      for (int ii = 0; ii < 16; ++ii) {
        int ll = ii ^ jj;
        if (ll > ii) {
          bool desc = ((ii & kk) == 0);
          u32 a = key[ii], b = key[ll];
          bool sw = desc ? (a < b) : (a > b);
          key[ii] = sw ? b : a;
          key[ll] = sw ? a : b;
        }
      }
    }
  }
  double dl = (double)dsum;
  for (int off = 32; off > 0; off >>= 1) dl += __shfl_down(dl, off, 64);
  if ((tid & 63) == 0) dred[tid >> 6] = dl;
#pragma unroll
  for (int o = 0; o < TOPK; ++o) lds[tid * TOPK + o] = key[o];
  __syncthreads();
  // merge tree: load both lists, merge-path in registers (no dependent LDS chains)
  for (int off = 128; off >= 1; off >>= 1) {
    if (tid < off) {
      u32 A[TOPK], B[TOPK];
#pragma unroll
      for (int o = 0; o < TOPK; ++o) {
        A[o] = lds[tid * TOPK + o];
        B[o] = lds[(tid + off) * TOPK + o];
      }
      u32 out[TOPK];
#pragma unroll
      for (int o = 0; o < TOPK; ++o) {
        u32 m = A[o] > B[o] ? A[o] : B[o];
#pragma unroll
        for (int p = 0; p < o; ++p) {
          u32 mn = A[p] < B[o - 1 - p] ? A[p] : B[o - 1 - p];
          m = m > mn ? m : mn;
        }
        out[o] = m;
      }
#pragma unroll
      for (int o = 0; o < TOPK; ++o) lds[tid * TOPK + o] = out[o];
    }
    __syncthreads();
  }
  if (tid == 0) {
#pragma unroll
    for (int o = 0; o < TOPK; ++o)
      topk[i * TOPK + o] = 4095 - (int)(lds[o] & 0xFFFu);
    pd[i] = dred[0] + dred[1] + dred[2] + dred[3];
  }
}

// ---------------- mutual-kNN lists ----------------
__global__ __launch_bounds__(64) void k_buildV(const int* __restrict__ topk,
                                               int* __restrict__ L,
                                               int* __restrict__ cnt) {
  int i = blockIdx.x * 64 + threadIdx.x;
  if (i >= N) return;
  int c = 0;
  for (int r = 0; r < TOPK; ++r) {
    int j = topk[i * TOPK + r];
    bool mut = false;
    for (int q = 0; q < TOPK; ++q) mut |= (topk[j * TOPK + q] == i);
    if (mut) L[i * TOPK + c++] = j;
  }
  cnt[i] = c;
}

// ---------------- sparse W_C loss: one 16-lane group per task, sd from Gsd ----------------
__global__ __launch_bounds__(256) void k_wc(const int* __restrict__ topk,
                                            const int* __restrict__ L,
                                            const int* __restrict__ cnt,
                                            const f16* __restrict__ Gsd,
                                            const float* __restrict__ rowsum,
                                            double* __restrict__ pw) {
  __shared__ double red[16];
  int tid = threadIdx.x;
  int grp = tid >> 4;
  int gl = tid & 15;
  int task = blockIdx.x * 16 + grp;
  int i = task / TOPK_HALF, m = task % TOPK_HALF;
  int r = topk[i * TOPK + m];
  int cr = cnt[r];
  float invmi = 1.0f / (rowsum[i] * INV_N);
  int lval = (gl < cr) ? L[r * TOPK + gl] : -1;
  int Lr[TOPK];
#pragma unroll
  for (int a = 0; a < TOPK; ++a) Lr[a] = __shfl(lval, a, 16);
  float contrib = 0.f;
  if (gl < cr) {
    int j = lval;
    if (j != i) {
      int cj = cnt[j];
      float mj = rowsum[j] * INV_N;
      float sr_ = f16tof(((const u16*)Gsd)[(size_t)i * N + j]);
      int lj[TOPK];
#pragma unroll
      for (int b = 0; b < TOPK; ++b) lj[b] = L[j * TOPK + b];
      int vv = 0;
#pragma unroll
      for (int b = 0; b < TOPK; ++b) {
        if (b < cj) {
#pragma unroll
          for (int a = 0; a < TOPK; ++a)
            vv += ((a < cr) && (lj[b] == Lr[a])) ? 1 : 0;
        }
      }
      float denom = (float)(cr > 1 ? cr : 1);
      float wgt = (float)vv / denom;
      float sdij = sr_ * invmi;
      float sdji = sr_ / mj;
      float Rij = fmaxf(1.0f - sdij, 0.0f); Rij *= Rij;
      float Rji = fmaxf(1.0f - sdji, 0.0f); Rji *= Rji;
      float Fij = sdij * sdij - Rij;
      float Fji = sdji * sdji - Rji;
      contrib = wgt * (Fij + Fji);
    }
  }
  double local = (double)contrib;
  local += __shfl_xor(local, 1, 16);
  local += __shfl_xor(local, 2, 16);
  local += __shfl_xor(local, 4, 16);
  local += __shfl_xor(local, 8, 16);
  if (gl == 0) red[grp] = local;
  __syncthreads();
  if (tid == 0) {
    double s = 0.0;
#pragma unroll
    for (int g = 0; g < 16; ++g) s += red[g];
    pw[blockIdx.x] = s * (1.0 / 20.0);
  }
}

// ---------------- final reduce ----------------
__global__ __launch_bounds__(256) void k_final(const double* __restrict__ pd,
                                               const double* __restrict__ pw,
                                               float* __restrict__ out) {
  int tid = threadIdx.x;
  double s = 0.0;
  for (int i = tid; i < N; i += 256) s += pd[i];
  for (int i = tid; i < WC_BLOCKS; i += 256) s += pw[i];
  for (int off = 32; off > 0; off >>= 1) s += __shfl_down(s, off, 64);
  __shared__ double red[4];
  if ((tid & 63) == 0) red[tid >> 6] = s;
  __syncthreads();
  if (tid == 0)
    out[0] = (float)((red[0] + red[1] + red[2] + red[3]) /
                     ((double)N * (double)(N - 1)));
}

extern "C" void kernel_launch(void* const* d_in, const int* in_sizes, int n_in,
                              void* d_out, int out_size, void* d_ws, size_t ws_size,
                              hipStream_t stream) {
  const float* s_emb = (const float*)d_in[0];
  const float* t_emb = (const float*)d_in[1];
  const int* ids = (const int*)d_in[2];
  float* out = (float*)d_out;

  char* ws = (char*)d_ws;
  size_t off = 0;
  bf16* snorm = (bf16*)(ws + off); off += (size_t)N * D * 2;        // 4 MB
  bf16* tnorm = (bf16*)(ws + off); off += (size_t)N * D * 2;        // 4 MB
  f16*  Gsd   = (f16*)(ws + off);  off += (size_t)N * N * 2;        // 32 MB
  f16*  Gwp   = (f16*)(ws + off);  off += (size_t)N * N * 2;        // 32 MB
  float* rsq_s = (float*)(ws + off); off += (size_t)N * 4;
  float* rsq_t = (float*)(ws + off); off += (size_t)N * 4;
  float* rowsum= (float*)(ws + off); off += (size_t)N * 4;
  int*   topk  = (int*)(ws + off);   off += (size_t)N * TOPK * 4;
  int*   L     = (int*)(ws + off);   off += (size_t)N * TOPK * 4;
  int*   cnt   = (int*)(ws + off);   off += (size_t)N * 4;
  off = (off + 15) & ~(size_t)15;
  double* pd   = (double*)(ws + off); off += (size_t)N * 8;
  double* pw   = (double*)(ws + off); off += (size_t)WC_BLOCKS * 8;

  k_normalize2<<<2 * N, 256, 0, stream>>>(s_emb, t_emb, snorm, tnorm,
                                          rsq_s, rsq_t, rowsum);
  k_dgram3<<<dim3(TRI_BLOCKS, 2), 256, 0, stream>>>(snorm, tnorm, rsq_s, rsq_t,
                                                    Gsd, Gwp, rowsum);
  k_rowpass<<<N, 256, 0, stream>>>(Gsd, Gwp, ids, rowsum, topk, pd);
  k_buildV<<<N / 64, 64, 0, stream>>>(topk, L, cnt);
  k_wc<<<WC_BLOCKS, 256, 0, stream>>>(topk, L, cnt, Gsd, rowsum, pw);
  k_final<<<1, 256, 0, stream>>>(pd, pw, out);
}